// Round 3
// baseline (546.829 us; speedup 1.0000x reference)
//
#include <hip/hip_runtime.h>
#include <hip/hip_bf16.h>
#include <math.h>

using bf16 = __hip_bfloat16;
typedef __attribute__((ext_vector_type(8))) short bf16x8;
typedef __attribute__((ext_vector_type(4))) float f32x4;

#define B_   2
#define T_   2048
#define D_   1024
#define NH_  16
#define DH_  64
#define MLP_ 4096
#define ROWS (B_ * T_)                 // 4096
#define BHTD ((size_t)32 * 2048 * 64)  // one of Q/K/V, elements

// async global->LDS, 16B per lane (dest must be linear: wave base + lane*16)
__device__ __forceinline__ void gload_lds16(const void* g, void* l) {
    __builtin_amdgcn_global_load_lds(
        (const __attribute__((address_space(1))) unsigned int*)g,
        (__attribute__((address_space(3))) unsigned int*)l, 16, 0, 0);
}

// ---------------- weight transpose-convert: W[K][N] f32 -> Wt[N][K] bf16 ----
__global__ void wtrans_kernel(const float* __restrict__ W, bf16* __restrict__ Wt,
                              int K, int N) {
    __shared__ float tile[32][33];
    int n0 = blockIdx.x * 32, k0 = blockIdx.y * 32;
    int tx = threadIdx.x, ty = threadIdx.y;  // 32 x 8
#pragma unroll
    for (int i = 0; i < 32; i += 8)
        tile[ty + i][tx] = W[(size_t)(k0 + ty + i) * N + n0 + tx];
    __syncthreads();
#pragma unroll
    for (int i = 0; i < 32; i += 8)
        Wt[(size_t)(n0 + ty + i) * K + k0 + tx] = __float2bfloat16(tile[tx][ty + i]);
}

// ---------------- per-head V transpose: V[bh][t][64] -> Vt[bh][64][t] -------
__global__ void transpose_v_kernel(const bf16* __restrict__ V, bf16* __restrict__ Vt) {
    __shared__ bf16 tile[32][33];
    int bh = blockIdx.z;
    int t0 = blockIdx.x * 32;
    int d0 = blockIdx.y * 32;
    int tx = threadIdx.x, ty = threadIdx.y;  // 32 x 8
    const bf16* src = V + (size_t)bh * T_ * 64;
    bf16* dst = Vt + (size_t)bh * 64 * T_;
#pragma unroll
    for (int i = 0; i < 32; i += 8)
        tile[ty + i][tx] = src[(size_t)(t0 + ty + i) * 64 + d0 + tx];
    __syncthreads();
#pragma unroll
    for (int i = 0; i < 32; i += 8)
        dst[(size_t)(d0 + ty + i) * T_ + t0 + tx] = tile[tx][ty + i];
}

// ---------------- LayerNorm (row of 1024) f32 -> bf16 ----------------------
__global__ void ln_kernel(const float* __restrict__ x, const float* __restrict__ g,
                          const float* __restrict__ bta, bf16* __restrict__ out) {
    int row = blockIdx.x;
    int t = threadIdx.x;  // 256 threads * float4
    float4 v = ((const float4*)(x + (size_t)row * D_))[t];
    float s1 = v.x + v.y + v.z + v.w;
    float s2 = v.x * v.x + v.y * v.y + v.z * v.z + v.w * v.w;
#pragma unroll
    for (int m = 1; m < 64; m <<= 1) {
        s1 += __shfl_xor(s1, m);
        s2 += __shfl_xor(s2, m);
    }
    __shared__ float red[8];
    int wid = t >> 6, lane = t & 63;
    if (lane == 0) { red[wid] = s1; red[4 + wid] = s2; }
    __syncthreads();
    s1 = red[0] + red[1] + red[2] + red[3];
    s2 = red[4] + red[5] + red[6] + red[7];
    float mu = s1 * (1.0f / D_);
    float var = s2 * (1.0f / D_) - mu * mu;
    float rs = rsqrtf(var + 1e-5f);
    float4 gv = ((const float4*)g)[t];
    float4 bv = ((const float4*)bta)[t];
    bf16* o = out + (size_t)row * D_ + t * 4;
    o[0] = __float2bfloat16((v.x - mu) * rs * gv.x + bv.x);
    o[1] = __float2bfloat16((v.y - mu) * rs * gv.y + bv.y);
    o[2] = __float2bfloat16((v.z - mu) * rs * gv.z + bv.z);
    o[3] = __float2bfloat16((v.w - mu) * rs * gv.w + bv.w);
}

// ---------------- GEMM: C[M][N] = A[M][K](bf16) @ Bt[N][K](bf16)^T ----------
// m97 structure: 128x128 tile, BK=64, linear LDS + global_load_lds width=16.
// 256 threads = 2x2 waves, each wave 64x64 (4x4 frags).
// EPI 0: qkv head-scatter (bf16).  EPI 1: +bias +resid -> f32.
// EPI 2: gelu(+bias) -> bf16.
template <int EPI>
__global__ __launch_bounds__(256) void gemm_bt(const bf16* __restrict__ A,
                                               const bf16* __restrict__ Bt,
                                               int N, int K,
                                               const float* __restrict__ bias,
                                               const float* __restrict__ resid,
                                               void* __restrict__ out) {
    __shared__ __align__(16) bf16 Asm[128 * 64];  // linear [row][64]
    __shared__ __align__(16) bf16 Bsm[128 * 64];
    int tid = threadIdx.x;
    int bm = blockIdx.y * 128;
    int bn = blockIdx.x * 128;
    int wid = tid >> 6, lane = tid & 63;
    int wr = wid >> 1, wc = wid & 1;
    f32x4 acc[4][4];
#pragma unroll
    for (int m = 0; m < 4; m++)
#pragma unroll
        for (int n = 0; n < 4; n++) acc[m][n] = (f32x4){0.f, 0.f, 0.f, 0.f};

    for (int k0 = 0; k0 < K; k0 += 64) {
        __syncthreads();
#pragma unroll
        for (int i = 0; i < 4; i++) {
            int c = tid + i * 256;          // 1024 16B-chunks per matrix
            int row = c >> 3, col8 = (c & 7) * 8;
            gload_lds16(&A[(size_t)(bm + row) * K + k0 + col8], &Asm[c * 8]);
            gload_lds16(&Bt[(size_t)(bn + row) * K + k0 + col8], &Bsm[c * 8]);
        }
        __syncthreads();
#pragma unroll
        for (int kk = 0; kk < 2; kk++) {
            bf16x8 af[4], bfr[4];
#pragma unroll
            for (int m = 0; m < 4; m++)
                af[m] = *(const bf16x8*)&Asm[(wr * 64 + m * 16 + (lane & 15)) * 64 + kk * 32 + (lane >> 4) * 8];
#pragma unroll
            for (int n = 0; n < 4; n++)
                bfr[n] = *(const bf16x8*)&Bsm[(wc * 64 + n * 16 + (lane & 15)) * 64 + kk * 32 + (lane >> 4) * 8];
#pragma unroll
            for (int m = 0; m < 4; m++)
#pragma unroll
                for (int n = 0; n < 4; n++)
                    acc[m][n] = __builtin_amdgcn_mfma_f32_16x16x32_bf16(af[m], bfr[n], acc[m][n], 0, 0, 0);
        }
    }
    int r0 = bm + wr * 64;
    int c0 = bn + wc * 64;
#pragma unroll
    for (int m = 0; m < 4; m++) {
#pragma unroll
        for (int n = 0; n < 4; n++) {
#pragma unroll
            for (int j = 0; j < 4; j++) {
                int r = r0 + m * 16 + (lane >> 4) * 4 + j;
                int c = c0 + n * 16 + (lane & 15);
                float v = acc[m][n][j];
                if constexpr (EPI == 0) {
                    int which = c >> 10, d = c & 1023;
                    int h = d >> 6, dh = d & 63;
                    int b = r >> 11, t = r & 2047;
                    ((bf16*)out)[(((size_t)which * 32 + b * 16 + h) * 2048 + t) * 64 + dh] =
                        __float2bfloat16(v);
                } else if constexpr (EPI == 1) {
                    ((float*)out)[(size_t)r * N + c] = v + bias[c] + resid[(size_t)r * N + c];
                } else {
                    float u = v + bias[c];
                    float ge = 0.5f * u * (1.0f + erff(u * 0.70710678118f));
                    ((bf16*)out)[(size_t)r * N + c] = __float2bfloat16(ge);
                }
            }
        }
    }
}

// ---------------- flash attention: per (bh, 64-q-row tile), KVBLK=128 -------
#define SCL 0.18033688011112042f  /* 0.125 * log2(e) — exp2 domain */
__global__ __launch_bounds__(256) void attn_kernel(const bf16* __restrict__ Q,
                                                   const bf16* __restrict__ Kt,
                                                   const bf16* __restrict__ Vt,
                                                   bf16* __restrict__ Y) {
    __shared__ __align__(16) bf16 Ksm[128][72];      // [key][dh], pad 8
    __shared__ __align__(16) bf16 Vsm[64][136];      // [dh][key], pad 8
    __shared__ __align__(16) bf16 Psm[4][16][136];   // per-wave P[q][key]
    int tid = threadIdx.x;
    int wid = tid >> 6, lane = tid & 63;
    int bh = blockIdx.y;
    int q0 = blockIdx.x * 64 + wid * 16;
    const bf16* Qb = Q + (size_t)bh * T_ * 64;
    const bf16* Kb = Kt + (size_t)bh * T_ * 64;
    const bf16* Vb = Vt + (size_t)bh * 64 * T_;

    bf16x8 aq[2];
#pragma unroll
    for (int kk = 0; kk < 2; kk++)
        aq[kk] = *(const bf16x8*)&Qb[(size_t)(q0 + (lane & 15)) * 64 + kk * 32 + (lane >> 4) * 8];

    float mrow[4], lrow[4];
    f32x4 o[4];
#pragma unroll
    for (int j = 0; j < 4; j++) { mrow[j] = -1e30f; lrow[j] = 0.f; }
#pragma unroll
    for (int n = 0; n < 4; n++) o[n] = (f32x4){0.f, 0.f, 0.f, 0.f};

    for (int kt = 0; kt < T_ / 128; kt++) {
        __syncthreads();
        // stage K tile: 128 keys x 64 dh
#pragma unroll
        for (int i = 0; i < 4; i++) {
            int c = tid + i * 256;
            int row = c >> 3, col8 = (c & 7) * 8;
            *(uint4*)&Ksm[row][col8] = *(const uint4*)&Kb[(size_t)(kt * 128 + row) * 64 + col8];
        }
        // stage V tile: 64 dh x 128 keys
#pragma unroll
        for (int i = 0; i < 4; i++) {
            int c = tid + i * 256;
            int row = c >> 4, col8 = (c & 15) * 8;
            *(uint4*)&Vsm[row][col8] = *(const uint4*)&Vb[(size_t)row * T_ + kt * 128 + col8];
        }
        __syncthreads();

        f32x4 s[8];
#pragma unroll
        for (int n = 0; n < 8; n++) {
            bf16x8 b0 = *(const bf16x8*)&Ksm[n * 16 + (lane & 15)][(lane >> 4) * 8];
            bf16x8 b1 = *(const bf16x8*)&Ksm[n * 16 + (lane & 15)][32 + (lane >> 4) * 8];
            s[n] = __builtin_amdgcn_mfma_f32_16x16x32_bf16(aq[0], b0, (f32x4){0.f, 0.f, 0.f, 0.f}, 0, 0, 0);
            s[n] = __builtin_amdgcn_mfma_f32_16x16x32_bf16(aq[1], b1, s[n], 0, 0, 0);
        }
#pragma unroll
        for (int n = 0; n < 8; n++) s[n] *= SCL;   // into 2^x domain

        float mnew[4], sc[4];
#pragma unroll
        for (int j = 0; j < 4; j++) {
            float mj = fmaxf(fmaxf(fmaxf(s[0][j], s[1][j]), fmaxf(s[2][j], s[3][j])),
                             fmaxf(fmaxf(s[4][j], s[5][j]), fmaxf(s[6][j], s[7][j])));
            mj = fmaxf(mj, __shfl_xor(mj, 1));
            mj = fmaxf(mj, __shfl_xor(mj, 2));
            mj = fmaxf(mj, __shfl_xor(mj, 4));
            mj = fmaxf(mj, __shfl_xor(mj, 8));
            float mn = fmaxf(mrow[j], mj);
            sc[j] = exp2f(mrow[j] - mn);
            mnew[j] = mn;
            mrow[j] = mn;
        }
        float psum[4] = {0.f, 0.f, 0.f, 0.f};
#pragma unroll
        for (int n = 0; n < 8; n++)
#pragma unroll
            for (int j = 0; j < 4; j++) {
                float pv = exp2f(s[n][j] - mnew[j]);
                s[n][j] = pv;
                psum[j] += pv;
            }
#pragma unroll
        for (int j = 0; j < 4; j++) {
            psum[j] += __shfl_xor(psum[j], 1);
            psum[j] += __shfl_xor(psum[j], 2);
            psum[j] += __shfl_xor(psum[j], 4);
            psum[j] += __shfl_xor(psum[j], 8);
            lrow[j] = lrow[j] * sc[j] + psum[j];
        }
#pragma unroll
        for (int n = 0; n < 4; n++)
#pragma unroll
            for (int j = 0; j < 4; j++) o[n][j] *= sc[j];

        // P -> LDS (per-wave) -> A-frags
#pragma unroll
        for (int n = 0; n < 8; n++)
#pragma unroll
            for (int j = 0; j < 4; j++)
                Psm[wid][(lane >> 4) * 4 + j][n * 16 + (lane & 15)] = __float2bfloat16(s[n][j]);

        bf16x8 pa[4];
#pragma unroll
        for (int kk = 0; kk < 4; kk++)
            pa[kk] = *(const bf16x8*)&Psm[wid][lane & 15][kk * 32 + (lane >> 4) * 8];

#pragma unroll
        for (int n = 0; n < 4; n++) {
#pragma unroll
            for (int ks = 0; ks < 4; ks++) {
                bf16x8 v = *(const bf16x8*)&Vsm[n * 16 + (lane & 15)][ks * 32 + (lane >> 4) * 8];
                o[n] = __builtin_amdgcn_mfma_f32_16x16x32_bf16(pa[ks], v, o[n], 0, 0, 0);
            }
        }
    }

    int b = bh >> 4, h = bh & 15;
#pragma unroll
    for (int j = 0; j < 4; j++) {
        float inv = 1.0f / lrow[j];
        int t = q0 + (lane >> 4) * 4 + j;
#pragma unroll
        for (int n = 0; n < 4; n++) {
            int c = h * 64 + n * 16 + (lane & 15);
            Y[((size_t)b * T_ + t) * D_ + c] = __float2bfloat16(o[n][j] * inv);
        }
    }
}

// ---------------------------------------------------------------------------
extern "C" void kernel_launch(void* const* d_in, const int* in_sizes, int n_in,
                              void* d_out, int out_size, void* d_ws, size_t ws_size,
                              hipStream_t stream) {
    const float* inputs = (const float*)d_in[0];
    // d_in[1] cond, d_in[2] attention_mask: unused by reference path
    const float* ln1_g = (const float*)d_in[3];
    const float* ln1_b = (const float*)d_in[4];
    const float* ln2_g = (const float*)d_in[5];
    const float* ln2_b = (const float*)d_in[6];
    const float* w_qkv = (const float*)d_in[7];
    const float* w_out = (const float*)d_in[8];
    const float* b_out = (const float*)d_in[9];
    const float* w1    = (const float*)d_in[10];
    const float* b1    = (const float*)d_in[11];
    const float* w2    = (const float*)d_in[12];
    const float* b2    = (const float*)d_in[13];

    char* p = (char*)d_ws;
    auto alloc = [&](size_t bytes) {
        void* r = (void*)p;
        p += (bytes + 255) & ~(size_t)255;
        return r;
    };
    bf16* x1     = (bf16*)alloc((size_t)ROWS * D_ * 2);
    bf16* wqkv_t = (bf16*)alloc((size_t)3 * D_ * D_ * 2);
    bf16* wout_t = (bf16*)alloc((size_t)D_ * D_ * 2);
    bf16* w1_t   = (bf16*)alloc((size_t)MLP_ * D_ * 2);
    bf16* w2_t   = (bf16*)alloc((size_t)D_ * MLP_ * 2);
    bf16* qkv    = (bf16*)alloc((size_t)3 * BHTD * 2);
    bf16* vt     = (bf16*)alloc((size_t)BHTD * 2);
    bf16* y      = (bf16*)alloc((size_t)ROWS * D_ * 2);
    float* x2    = (float*)alloc((size_t)ROWS * D_ * 4);
    bf16* h2     = (bf16*)alloc((size_t)ROWS * D_ * 2);
    bf16* act    = (bf16*)alloc((size_t)ROWS * MLP_ * 2);

    dim3 tb(32, 8);
    wtrans_kernel<<<dim3(3 * D_ / 32, D_ / 32), tb, 0, stream>>>(w_qkv, wqkv_t, D_, 3 * D_);
    wtrans_kernel<<<dim3(D_ / 32, D_ / 32), tb, 0, stream>>>(w_out, wout_t, D_, D_);
    wtrans_kernel<<<dim3(MLP_ / 32, D_ / 32), tb, 0, stream>>>(w1, w1_t, D_, MLP_);
    wtrans_kernel<<<dim3(D_ / 32, MLP_ / 32), tb, 0, stream>>>(w2, w2_t, MLP_, D_);

    ln_kernel<<<ROWS, 256, 0, stream>>>(inputs, ln1_g, ln1_b, x1);

    gemm_bt<0><<<dim3(3 * D_ / 128, ROWS / 128), 256, 0, stream>>>(
        x1, wqkv_t, 3 * D_, D_, nullptr, nullptr, (void*)qkv);

    transpose_v_kernel<<<dim3(T_ / 32, 2, 32), tb, 0, stream>>>(qkv + 2 * BHTD, vt);

    attn_kernel<<<dim3(T_ / 64, 32), 256, 0, stream>>>(qkv, qkv + BHTD, vt, y);

    gemm_bt<1><<<dim3(D_ / 128, ROWS / 128), 256, 0, stream>>>(
        y, wout_t, D_, D_, b_out, inputs, (void*)x2);

    ln_kernel<<<ROWS, 256, 0, stream>>>(x2, ln2_g, ln2_b, h2);

    gemm_bt<2><<<dim3(MLP_ / 128, ROWS / 128), 256, 0, stream>>>(
        h2, w1_t, MLP_, D_, b1, nullptr, (void*)act);

    gemm_bt<1><<<dim3(D_ / 128, ROWS / 128), 256, 0, stream>>>(
        act, w2_t, D_, MLP_, b2, x2, d_out);
}

// Round 5
// 505.771 us; speedup vs baseline: 1.0812x; 1.0812x over previous
//
#include <hip/hip_runtime.h>
#include <hip/hip_bf16.h>
#include <math.h>

using bf16 = __hip_bfloat16;
typedef __attribute__((ext_vector_type(8))) short bf16x8;
typedef __attribute__((ext_vector_type(4))) float f32x4;

#define B_   2
#define T_   2048
#define D_   1024
#define NH_  16
#define DH_  64
#define MLP_ 4096
#define ROWS (B_ * T_)                 // 4096
#define BHTD ((size_t)32 * 2048 * 64)  // one of Q/K/V, elements

// async global->LDS, 16B per lane (dest must be linear: wave base + lane*16)
__device__ __forceinline__ void gload_lds16(const void* g, void* l) {
    __builtin_amdgcn_global_load_lds(
        (const __attribute__((address_space(1))) unsigned int*)g,
        (__attribute__((address_space(3))) unsigned int*)l, 16, 0, 0);
}

// ---------------- weight transpose-convert: W[K][N] f32 -> Wt[N][K] bf16 ----
__global__ void wtrans_kernel(const float* __restrict__ W, bf16* __restrict__ Wt,
                              int K, int N) {
    __shared__ float tile[32][33];
    int n0 = blockIdx.x * 32, k0 = blockIdx.y * 32;
    int tx = threadIdx.x, ty = threadIdx.y;  // 32 x 8
#pragma unroll
    for (int i = 0; i < 32; i += 8)
        tile[ty + i][tx] = W[(size_t)(k0 + ty + i) * N + n0 + tx];
    __syncthreads();
#pragma unroll
    for (int i = 0; i < 32; i += 8)
        Wt[(size_t)(n0 + ty + i) * K + k0 + tx] = __float2bfloat16(tile[tx][ty + i]);
}

// ---------------- per-head V transpose: V[bh][t][64] -> Vt[bh][64][t] -------
__global__ void transpose_v_kernel(const bf16* __restrict__ V, bf16* __restrict__ Vt) {
    __shared__ bf16 tile[32][33];
    int bh = blockIdx.z;
    int t0 = blockIdx.x * 32;
    int d0 = blockIdx.y * 32;
    int tx = threadIdx.x, ty = threadIdx.y;  // 32 x 8
    const bf16* src = V + (size_t)bh * T_ * 64;
    bf16* dst = Vt + (size_t)bh * 64 * T_;
#pragma unroll
    for (int i = 0; i < 32; i += 8)
        tile[ty + i][tx] = src[(size_t)(t0 + ty + i) * 64 + d0 + tx];
    __syncthreads();
#pragma unroll
    for (int i = 0; i < 32; i += 8)
        dst[(size_t)(d0 + ty + i) * T_ + t0 + tx] = tile[tx][ty + i];
}

// ---------------- LayerNorm (row of 1024) f32 -> bf16 ----------------------
__global__ void ln_kernel(const float* __restrict__ x, const float* __restrict__ g,
                          const float* __restrict__ bta, bf16* __restrict__ out) {
    int row = blockIdx.x;
    int t = threadIdx.x;  // 256 threads * float4
    float4 v = ((const float4*)(x + (size_t)row * D_))[t];
    float s1 = v.x + v.y + v.z + v.w;
    float s2 = v.x * v.x + v.y * v.y + v.z * v.z + v.w * v.w;
#pragma unroll
    for (int m = 1; m < 64; m <<= 1) {
        s1 += __shfl_xor(s1, m);
        s2 += __shfl_xor(s2, m);
    }
    __shared__ float red[8];
    int wid = t >> 6, lane = t & 63;
    if (lane == 0) { red[wid] = s1; red[4 + wid] = s2; }
    __syncthreads();
    s1 = red[0] + red[1] + red[2] + red[3];
    s2 = red[4] + red[5] + red[6] + red[7];
    float mu = s1 * (1.0f / D_);
    float var = s2 * (1.0f / D_) - mu * mu;
    float rs = rsqrtf(var + 1e-5f);
    float4 gv = ((const float4*)g)[t];
    float4 bv = ((const float4*)bta)[t];
    bf16* o = out + (size_t)row * D_ + t * 4;
    o[0] = __float2bfloat16((v.x - mu) * rs * gv.x + bv.x);
    o[1] = __float2bfloat16((v.y - mu) * rs * gv.y + bv.y);
    o[2] = __float2bfloat16((v.z - mu) * rs * gv.z + bv.z);
    o[3] = __float2bfloat16((v.w - mu) * rs * gv.w + bv.w);
}

// ---------------- GEMM: C[M][N] = A[M][K](bf16) @ Bt[N][K](bf16)^T ----------
// m97 structure: 128x128 tile, BK=64, linear LDS + global_load_lds width=16.
// XCD-chunked blockIdx swizzle (T1; all grids are %8==0 -> bijective).
// EPI 0: qkv head-scatter (bf16).  EPI 1: +bias +resid -> f32.
// EPI 2: gelu(+bias) -> bf16.
template <int EPI>
__global__ __launch_bounds__(256) void gemm_bt(const bf16* __restrict__ A,
                                               const bf16* __restrict__ Bt,
                                               int N, int K,
                                               const float* __restrict__ bias,
                                               const float* __restrict__ resid,
                                               void* __restrict__ out) {
    __shared__ __align__(16) bf16 Asm[128 * 64];  // linear [row][64]
    __shared__ __align__(16) bf16 Bsm[128 * 64];
    int tid = threadIdx.x;
    // XCD swizzle: contiguous chunks of the linear wg id per XCD
    int nwg = gridDim.x * gridDim.y;
    int wg = blockIdx.y * gridDim.x + blockIdx.x;
    int swz = (wg & 7) * (nwg >> 3) + (wg >> 3);
    int bm = (swz / gridDim.x) * 128;
    int bn = (swz % gridDim.x) * 128;
    int wid = tid >> 6, lane = tid & 63;
    int wr = wid >> 1, wc = wid & 1;
    f32x4 acc[4][4];
#pragma unroll
    for (int m = 0; m < 4; m++)
#pragma unroll
        for (int n = 0; n < 4; n++) acc[m][n] = (f32x4){0.f, 0.f, 0.f, 0.f};

    for (int k0 = 0; k0 < K; k0 += 64) {
        __syncthreads();
#pragma unroll
        for (int i = 0; i < 4; i++) {
            int c = tid + i * 256;          // 1024 16B-chunks per matrix
            int row = c >> 3, col8 = (c & 7) * 8;
            gload_lds16(&A[(size_t)(bm + row) * K + k0 + col8], &Asm[c * 8]);
            gload_lds16(&Bt[(size_t)(bn + row) * K + k0 + col8], &Bsm[c * 8]);
        }
        __syncthreads();
#pragma unroll
        for (int kk = 0; kk < 2; kk++) {
            bf16x8 af[4], bfr[4];
#pragma unroll
            for (int m = 0; m < 4; m++)
                af[m] = *(const bf16x8*)&Asm[(wr * 64 + m * 16 + (lane & 15)) * 64 + kk * 32 + (lane >> 4) * 8];
#pragma unroll
            for (int n = 0; n < 4; n++)
                bfr[n] = *(const bf16x8*)&Bsm[(wc * 64 + n * 16 + (lane & 15)) * 64 + kk * 32 + (lane >> 4) * 8];
#pragma unroll
            for (int m = 0; m < 4; m++)
#pragma unroll
                for (int n = 0; n < 4; n++)
                    acc[m][n] = __builtin_amdgcn_mfma_f32_16x16x32_bf16(af[m], bfr[n], acc[m][n], 0, 0, 0);
        }
    }
    int r0 = bm + wr * 64;
    int c0 = bn + wc * 64;
#pragma unroll
    for (int m = 0; m < 4; m++) {
#pragma unroll
        for (int n = 0; n < 4; n++) {
#pragma unroll
            for (int j = 0; j < 4; j++) {
                int r = r0 + m * 16 + (lane >> 4) * 4 + j;
                int c = c0 + n * 16 + (lane & 15);
                float v = acc[m][n][j];
                if constexpr (EPI == 0) {
                    int which = c >> 10, d = c & 1023;
                    int h = d >> 6, dh = d & 63;
                    int b = r >> 11, t = r & 2047;
                    ((bf16*)out)[(((size_t)which * 32 + b * 16 + h) * 2048 + t) * 64 + dh] =
                        __float2bfloat16(v);
                } else if constexpr (EPI == 1) {
                    ((float*)out)[(size_t)r * N + c] = v + bias[c] + resid[(size_t)r * N + c];
                } else {
                    float u = v + bias[c];
                    float ge = 0.5f * u * (1.0f + erff(u * 0.70710678118f));
                    ((bf16*)out)[(size_t)r * N + c] = __float2bfloat16(ge);
                }
            }
        }
    }
}

// ---------------- flash attention: 8 waves, 128 q-rows/block, KVBLK=64 ------
#define SCL 0.18033688011112042f  /* 0.125 * log2(e) — exp2 domain */
__global__ __launch_bounds__(512) void attn_kernel(const bf16* __restrict__ Q,
                                                   const bf16* __restrict__ Kt,
                                                   const bf16* __restrict__ Vt,
                                                   bf16* __restrict__ Y) {
    __shared__ __align__(16) bf16 Ksm[64][72];
    __shared__ __align__(16) bf16 Vsm[64][72];       // Vsm[dh][key]
    __shared__ __align__(16) bf16 Psm[8][16][72];    // per-wave P[q][key]
    int tid = threadIdx.x;
    int wid = tid >> 6, lane = tid & 63;
    int bh = blockIdx.y;
    int q0 = blockIdx.x * 128 + wid * 16;
    const bf16* Qb = Q + (size_t)bh * T_ * 64;
    const bf16* Kb = Kt + (size_t)bh * T_ * 64;
    const bf16* Vb = Vt + (size_t)bh * 64 * T_;

    bf16x8 aq[2];
#pragma unroll
    for (int kk = 0; kk < 2; kk++)
        aq[kk] = *(const bf16x8*)&Qb[(size_t)(q0 + (lane & 15)) * 64 + kk * 32 + (lane >> 4) * 8];

    float mrow[4], lrow[4];
    f32x4 o[4];
#pragma unroll
    for (int j = 0; j < 4; j++) { mrow[j] = -1e30f; lrow[j] = 0.f; }
#pragma unroll
    for (int n = 0; n < 4; n++) o[n] = (f32x4){0.f, 0.f, 0.f, 0.f};

    for (int kt = 0; kt < T_ / 64; kt++) {
        __syncthreads();
        // stage K tile (64x64) and V tile (64x64): one uint4 chunk per thread
        {
            int row = tid >> 3, col8 = (tid & 7) * 8;
            *(uint4*)&Ksm[row][col8] = *(const uint4*)&Kb[(size_t)(kt * 64 + row) * 64 + col8];
            *(uint4*)&Vsm[row][col8] = *(const uint4*)&Vb[(size_t)row * T_ + kt * 64 + col8];
        }
        __syncthreads();

        f32x4 s[4];
#pragma unroll
        for (int n = 0; n < 4; n++) {
            bf16x8 b0 = *(const bf16x8*)&Ksm[n * 16 + (lane & 15)][(lane >> 4) * 8];
            bf16x8 b1 = *(const bf16x8*)&Ksm[n * 16 + (lane & 15)][32 + (lane >> 4) * 8];
            s[n] = __builtin_amdgcn_mfma_f32_16x16x32_bf16(aq[0], b0, (f32x4){0.f, 0.f, 0.f, 0.f}, 0, 0, 0);
            s[n] = __builtin_amdgcn_mfma_f32_16x16x32_bf16(aq[1], b1, s[n], 0, 0, 0);
        }
#pragma unroll
        for (int n = 0; n < 4; n++) s[n] *= SCL;   // into 2^x domain

        float mnew[4], sc[4];
#pragma unroll
        for (int j = 0; j < 4; j++) {
            float mj = fmaxf(fmaxf(s[0][j], s[1][j]), fmaxf(s[2][j], s[3][j]));
            mj = fmaxf(mj, __shfl_xor(mj, 1));
            mj = fmaxf(mj, __shfl_xor(mj, 2));
            mj = fmaxf(mj, __shfl_xor(mj, 4));
            mj = fmaxf(mj, __shfl_xor(mj, 8));
            float mn = fmaxf(mrow[j], mj);
            sc[j] = exp2f(mrow[j] - mn);
            mnew[j] = mn;
            mrow[j] = mn;
        }
        float psum[4] = {0.f, 0.f, 0.f, 0.f};
#pragma unroll
        for (int n = 0; n < 4; n++)
#pragma unroll
            for (int j = 0; j < 4; j++) {
                float pv = exp2f(s[n][j] - mnew[j]);
                s[n][j] = pv;
                psum[j] += pv;
            }
#pragma unroll
        for (int j = 0; j < 4; j++) {
            psum[j] += __shfl_xor(psum[j], 1);
            psum[j] += __shfl_xor(psum[j], 2);
            psum[j] += __shfl_xor(psum[j], 4);
            psum[j] += __shfl_xor(psum[j], 8);
            lrow[j] = lrow[j] * sc[j] + psum[j];
        }
#pragma unroll
        for (int n = 0; n < 4; n++)
#pragma unroll
            for (int j = 0; j < 4; j++) o[n][j] *= sc[j];

        // P -> LDS (per-wave) -> A-frags
#pragma unroll
        for (int n = 0; n < 4; n++)
#pragma unroll
            for (int j = 0; j < 4; j++)
                Psm[wid][(lane >> 4) * 4 + j][n * 16 + (lane & 15)] = __float2bfloat16(s[n][j]);

        bf16x8 pa[2];
#pragma unroll
        for (int kk = 0; kk < 2; kk++)
            pa[kk] = *(const bf16x8*)&Psm[wid][lane & 15][kk * 32 + (lane >> 4) * 8];

#pragma unroll
        for (int n = 0; n < 4; n++) {
            bf16x8 v0 = *(const bf16x8*)&Vsm[n * 16 + (lane & 15)][(lane >> 4) * 8];
            bf16x8 v1 = *(const bf16x8*)&Vsm[n * 16 + (lane & 15)][32 + (lane >> 4) * 8];
            o[n] = __builtin_amdgcn_mfma_f32_16x16x32_bf16(pa[0], v0, o[n], 0, 0, 0);
            o[n] = __builtin_amdgcn_mfma_f32_16x16x32_bf16(pa[1], v1, o[n], 0, 0, 0);
        }
    }

    int b = bh >> 4, h = bh & 15;
#pragma unroll
    for (int j = 0; j < 4; j++) {
        float inv = 1.0f / lrow[j];
        int t = q0 + (lane >> 4) * 4 + j;
#pragma unroll
        for (int n = 0; n < 4; n++) {
            int c = h * 64 + n * 16 + (lane & 15);
            Y[((size_t)b * T_ + t) * D_ + c] = __float2bfloat16(o[n][j] * inv);
        }
    }
}

// ---------------------------------------------------------------------------
extern "C" void kernel_launch(void* const* d_in, const int* in_sizes, int n_in,
                              void* d_out, int out_size, void* d_ws, size_t ws_size,
                              hipStream_t stream) {
    const float* inputs = (const float*)d_in[0];
    // d_in[1] cond, d_in[2] attention_mask: unused by reference path
    const float* ln1_g = (const float*)d_in[3];
    const float* ln1_b = (const float*)d_in[4];
    const float* ln2_g = (const float*)d_in[5];
    const float* ln2_b = (const float*)d_in[6];
    const float* w_qkv = (const float*)d_in[7];
    const float* w_out = (const float*)d_in[8];
    const float* b_out = (const float*)d_in[9];
    const float* w1    = (const float*)d_in[10];
    const float* b1    = (const float*)d_in[11];
    const float* w2    = (const float*)d_in[12];
    const float* b2    = (const float*)d_in[13];

    char* p = (char*)d_ws;
    auto alloc = [&](size_t bytes) {
        void* r = (void*)p;
        p += (bytes + 255) & ~(size_t)255;
        return r;
    };
    bf16* x1     = (bf16*)alloc((size_t)ROWS * D_ * 2);
    bf16* wqkv_t = (bf16*)alloc((size_t)3 * D_ * D_ * 2);
    bf16* wout_t = (bf16*)alloc((size_t)D_ * D_ * 2);
    bf16* w1_t   = (bf16*)alloc((size_t)MLP_ * D_ * 2);
    bf16* w2_t   = (bf16*)alloc((size_t)D_ * MLP_ * 2);
    bf16* qkv    = (bf16*)alloc((size_t)3 * BHTD * 2);
    bf16* vt     = (bf16*)alloc((size_t)BHTD * 2);
    bf16* y      = (bf16*)alloc((size_t)ROWS * D_ * 2);
    float* x2    = (float*)alloc((size_t)ROWS * D_ * 4);
    bf16* h2     = (bf16*)alloc((size_t)ROWS * D_ * 2);
    bf16* act    = (bf16*)alloc((size_t)ROWS * MLP_ * 2);

    dim3 tb(32, 8);
    wtrans_kernel<<<dim3(3 * D_ / 32, D_ / 32), tb, 0, stream>>>(w_qkv, wqkv_t, D_, 3 * D_);
    wtrans_kernel<<<dim3(D_ / 32, D_ / 32), tb, 0, stream>>>(w_out, wout_t, D_, D_);
    wtrans_kernel<<<dim3(MLP_ / 32, D_ / 32), tb, 0, stream>>>(w1, w1_t, D_, MLP_);
    wtrans_kernel<<<dim3(D_ / 32, MLP_ / 32), tb, 0, stream>>>(w2, w2_t, MLP_, D_);

    ln_kernel<<<ROWS, 256, 0, stream>>>(inputs, ln1_g, ln1_b, x1);

    gemm_bt<0><<<dim3(3 * D_ / 128, ROWS / 128), 256, 0, stream>>>(
        x1, wqkv_t, 3 * D_, D_, nullptr, nullptr, (void*)qkv);

    transpose_v_kernel<<<dim3(T_ / 32, 2, 32), tb, 0, stream>>>(qkv + 2 * BHTD, vt);

    attn_kernel<<<dim3(T_ / 128, 32), 512, 0, stream>>>(qkv, qkv + BHTD, vt, y);

    gemm_bt<1><<<dim3(D_ / 128, ROWS / 128), 256, 0, stream>>>(
        y, wout_t, D_, D_, b_out, inputs, (void*)x2);

    ln_kernel<<<ROWS, 256, 0, stream>>>(x2, ln2_g, ln2_b, h2);

    gemm_bt<2><<<dim3(MLP_ / 128, ROWS / 128), 256, 0, stream>>>(
        h2, w1_t, MLP_, D_, b1, nullptr, (void*)act);

    gemm_bt<1><<<dim3(D_ / 128, ROWS / 128), 256, 0, stream>>>(
        act, w2_t, D_, MLP_, b2, x2, d_out);
}

// Round 6
// 495.087 us; speedup vs baseline: 1.1045x; 1.0216x over previous
//
#include <hip/hip_runtime.h>
#include <hip/hip_bf16.h>
#include <math.h>

using bf16 = __hip_bfloat16;
typedef __attribute__((ext_vector_type(8))) short bf16x8;
typedef __attribute__((ext_vector_type(4))) float f32x4;

#define B_   2
#define T_   2048
#define D_   1024
#define NH_  16
#define DH_  64
#define MLP_ 4096
#define ROWS (B_ * T_)                 // 4096
#define BHTD ((size_t)32 * 2048 * 64)  // one of Q/K/V, elements

// async global->LDS, 16B per lane (dest must be linear: wave base + lane*16)
__device__ __forceinline__ void gload_lds16(const void* g, void* l) {
    __builtin_amdgcn_global_load_lds(
        (const __attribute__((address_space(1))) unsigned int*)g,
        (__attribute__((address_space(3))) unsigned int*)l, 16, 0, 0);
}

// ---------------- weight transpose-convert: W[K][N] f32 -> Wt[N][K] bf16 ----
__global__ void wtrans_kernel(const float* __restrict__ W, bf16* __restrict__ Wt,
                              int K, int N) {
    __shared__ float tile[32][33];
    int n0 = blockIdx.x * 32, k0 = blockIdx.y * 32;
    int tx = threadIdx.x, ty = threadIdx.y;  // 32 x 8
#pragma unroll
    for (int i = 0; i < 32; i += 8)
        tile[ty + i][tx] = W[(size_t)(k0 + ty + i) * N + n0 + tx];
    __syncthreads();
#pragma unroll
    for (int i = 0; i < 32; i += 8)
        Wt[(size_t)(n0 + ty + i) * K + k0 + tx] = __float2bfloat16(tile[tx][ty + i]);
}

// ---------------- per-head V transpose: V[bh][t][64] -> Vt[bh][64][t] -------
__global__ void transpose_v_kernel(const bf16* __restrict__ V, bf16* __restrict__ Vt) {
    __shared__ bf16 tile[32][33];
    int bh = blockIdx.z;
    int t0 = blockIdx.x * 32;
    int d0 = blockIdx.y * 32;
    int tx = threadIdx.x, ty = threadIdx.y;  // 32 x 8
    const bf16* src = V + (size_t)bh * T_ * 64;
    bf16* dst = Vt + (size_t)bh * 64 * T_;
#pragma unroll
    for (int i = 0; i < 32; i += 8)
        tile[ty + i][tx] = src[(size_t)(t0 + ty + i) * 64 + d0 + tx];
    __syncthreads();
#pragma unroll
    for (int i = 0; i < 32; i += 8)
        dst[(size_t)(d0 + ty + i) * T_ + t0 + tx] = tile[tx][ty + i];
}

// ---------------- LayerNorm (row of 1024) f32 -> bf16 ----------------------
__global__ void ln_kernel(const float* __restrict__ x, const float* __restrict__ g,
                          const float* __restrict__ bta, bf16* __restrict__ out) {
    int row = blockIdx.x;
    int t = threadIdx.x;  // 256 threads * float4
    float4 v = ((const float4*)(x + (size_t)row * D_))[t];
    float s1 = v.x + v.y + v.z + v.w;
    float s2 = v.x * v.x + v.y * v.y + v.z * v.z + v.w * v.w;
#pragma unroll
    for (int m = 1; m < 64; m <<= 1) {
        s1 += __shfl_xor(s1, m);
        s2 += __shfl_xor(s2, m);
    }
    __shared__ float red[8];
    int wid = t >> 6, lane = t & 63;
    if (lane == 0) { red[wid] = s1; red[4 + wid] = s2; }
    __syncthreads();
    s1 = red[0] + red[1] + red[2] + red[3];
    s2 = red[4] + red[5] + red[6] + red[7];
    float mu = s1 * (1.0f / D_);
    float var = s2 * (1.0f / D_) - mu * mu;
    float rs = rsqrtf(var + 1e-5f);
    float4 gv = ((const float4*)g)[t];
    float4 bv = ((const float4*)bta)[t];
    bf16* o = out + (size_t)row * D_ + t * 4;
    o[0] = __float2bfloat16((v.x - mu) * rs * gv.x + bv.x);
    o[1] = __float2bfloat16((v.y - mu) * rs * gv.y + bv.y);
    o[2] = __float2bfloat16((v.z - mu) * rs * gv.z + bv.z);
    o[3] = __float2bfloat16((v.w - mu) * rs * gv.w + bv.w);
}

// ---------------- GEMM: C[M][N] = A[M][K](bf16) @ Bt[N][K](bf16)^T ----------
// m97 structure: BMx128 tile, BK=64, linear LDS + global_load_lds width=16.
// BM=128: 2x2 waves, wave 64x64 (4x4 frags).  BM=64: wave 32x64 (2x4 frags)
//   -> doubles block count for the N=1024 GEMMs (out/mlp2): 256->512 blocks,
//      2 blocks/CU gives implicit wave overlap across the barrier drain (m114).
// EPI 0: qkv head-scatter (bf16).  EPI 1: +bias +resid -> f32.
// EPI 2: gelu(+bias) -> bf16.
template <int EPI, int BM>
__global__ __launch_bounds__(256) void gemm_bt(const bf16* __restrict__ A,
                                               const bf16* __restrict__ Bt,
                                               int N, int K,
                                               const float* __restrict__ bias,
                                               const float* __restrict__ resid,
                                               void* __restrict__ out) {
    constexpr int MF = BM / 32;                   // m-frags per wave
    __shared__ __align__(16) bf16 Asm[BM * 64];   // linear [row][64]
    __shared__ __align__(16) bf16 Bsm[128 * 64];
    int tid = threadIdx.x;
    // XCD swizzle: contiguous chunks of the linear wg id per XCD (nwg % 8 == 0)
    int nwg = gridDim.x * gridDim.y;
    int wg = blockIdx.y * gridDim.x + blockIdx.x;
    int swz = (wg & 7) * (nwg >> 3) + (wg >> 3);
    int bm = (swz / gridDim.x) * BM;
    int bn = (swz % gridDim.x) * 128;
    int wid = tid >> 6, lane = tid & 63;
    int wr = wid >> 1, wc = wid & 1;
    f32x4 acc[MF][4];
#pragma unroll
    for (int m = 0; m < MF; m++)
#pragma unroll
        for (int n = 0; n < 4; n++) acc[m][n] = (f32x4){0.f, 0.f, 0.f, 0.f};

    for (int k0 = 0; k0 < K; k0 += 64) {
        __syncthreads();
#pragma unroll
        for (int i = 0; i < BM * 8 / 256; i++) {
            int c = tid + i * 256;
            int row = c >> 3, col8 = (c & 7) * 8;
            gload_lds16(&A[(size_t)(bm + row) * K + k0 + col8], &Asm[c * 8]);
        }
#pragma unroll
        for (int i = 0; i < 4; i++) {
            int c = tid + i * 256;
            int row = c >> 3, col8 = (c & 7) * 8;
            gload_lds16(&Bt[(size_t)(bn + row) * K + k0 + col8], &Bsm[c * 8]);
        }
        __syncthreads();
#pragma unroll
        for (int kk = 0; kk < 2; kk++) {
            bf16x8 af[MF], bfr[4];
#pragma unroll
            for (int m = 0; m < MF; m++)
                af[m] = *(const bf16x8*)&Asm[(wr * (BM / 2) + m * 16 + (lane & 15)) * 64 + kk * 32 + (lane >> 4) * 8];
#pragma unroll
            for (int n = 0; n < 4; n++)
                bfr[n] = *(const bf16x8*)&Bsm[(wc * 64 + n * 16 + (lane & 15)) * 64 + kk * 32 + (lane >> 4) * 8];
#pragma unroll
            for (int m = 0; m < MF; m++)
#pragma unroll
                for (int n = 0; n < 4; n++)
                    acc[m][n] = __builtin_amdgcn_mfma_f32_16x16x32_bf16(af[m], bfr[n], acc[m][n], 0, 0, 0);
        }
    }
    int r0 = bm + wr * (BM / 2);
    int c0 = bn + wc * 64;
#pragma unroll
    for (int m = 0; m < MF; m++) {
#pragma unroll
        for (int n = 0; n < 4; n++) {
#pragma unroll
            for (int j = 0; j < 4; j++) {
                int r = r0 + m * 16 + (lane >> 4) * 4 + j;
                int c = c0 + n * 16 + (lane & 15);
                float v = acc[m][n][j];
                if constexpr (EPI == 0) {
                    int which = c >> 10, d = c & 1023;
                    int h = d >> 6, dh = d & 63;
                    int b = r >> 11, t = r & 2047;
                    ((bf16*)out)[(((size_t)which * 32 + b * 16 + h) * 2048 + t) * 64 + dh] =
                        __float2bfloat16(v);
                } else if constexpr (EPI == 1) {
                    ((float*)out)[(size_t)r * N + c] = v + bias[c] + resid[(size_t)r * N + c];
                } else {
                    float u = v + bias[c];
                    float ge = 0.5f * u * (1.0f + erff(u * 0.70710678118f));
                    ((bf16*)out)[(size_t)r * N + c] = __float2bfloat16(ge);
                }
            }
        }
    }
}

// ---------------- flash attention: 8 waves, 128 q-rows/block, KVBLK=64 ------
#define SCL 0.18033688011112042f  /* 0.125 * log2(e) — exp2 domain */
__global__ __launch_bounds__(512) void attn_kernel(const bf16* __restrict__ Q,
                                                   const bf16* __restrict__ Kt,
                                                   const bf16* __restrict__ Vt,
                                                   bf16* __restrict__ Y) {
    __shared__ __align__(16) bf16 Ksm[64][72];
    __shared__ __align__(16) bf16 Vsm[64][72];       // Vsm[dh][key]
    __shared__ __align__(16) bf16 Psm[8][16][72];    // per-wave P[q][key]
    int tid = threadIdx.x;
    int wid = tid >> 6, lane = tid & 63;
    int bh = blockIdx.y;
    int q0 = blockIdx.x * 128 + wid * 16;
    const bf16* Qb = Q + (size_t)bh * T_ * 64;
    const bf16* Kb = Kt + (size_t)bh * T_ * 64;
    const bf16* Vb = Vt + (size_t)bh * 64 * T_;

    bf16x8 aq[2];
#pragma unroll
    for (int kk = 0; kk < 2; kk++)
        aq[kk] = *(const bf16x8*)&Qb[(size_t)(q0 + (lane & 15)) * 64 + kk * 32 + (lane >> 4) * 8];

    float mrow[4], lrow[4];
    f32x4 o[4];
#pragma unroll
    for (int j = 0; j < 4; j++) { mrow[j] = -1e30f; lrow[j] = 0.f; }
#pragma unroll
    for (int n = 0; n < 4; n++) o[n] = (f32x4){0.f, 0.f, 0.f, 0.f};

    for (int kt = 0; kt < T_ / 64; kt++) {
        __syncthreads();
        // stage K tile (64x64) and V tile (64x64): one uint4 chunk per thread
        {
            int row = tid >> 3, col8 = (tid & 7) * 8;
            *(uint4*)&Ksm[row][col8] = *(const uint4*)&Kb[(size_t)(kt * 64 + row) * 64 + col8];
            *(uint4*)&Vsm[row][col8] = *(const uint4*)&Vb[(size_t)row * T_ + kt * 64 + col8];
        }
        __syncthreads();

        f32x4 s[4];
#pragma unroll
        for (int n = 0; n < 4; n++) {
            bf16x8 b0 = *(const bf16x8*)&Ksm[n * 16 + (lane & 15)][(lane >> 4) * 8];
            bf16x8 b1 = *(const bf16x8*)&Ksm[n * 16 + (lane & 15)][32 + (lane >> 4) * 8];
            s[n] = __builtin_amdgcn_mfma_f32_16x16x32_bf16(aq[0], b0, (f32x4){0.f, 0.f, 0.f, 0.f}, 0, 0, 0);
            s[n] = __builtin_amdgcn_mfma_f32_16x16x32_bf16(aq[1], b1, s[n], 0, 0, 0);
        }
#pragma unroll
        for (int n = 0; n < 4; n++) s[n] *= SCL;   // into 2^x domain

        // tile max per q-row (16-lane group reduce)
        float mjr[4], dm = -1e30f;
#pragma unroll
        for (int j = 0; j < 4; j++) {
            float mj = fmaxf(fmaxf(s[0][j], s[1][j]), fmaxf(s[2][j], s[3][j]));
            mj = fmaxf(mj, __shfl_xor(mj, 1));
            mj = fmaxf(mj, __shfl_xor(mj, 2));
            mj = fmaxf(mj, __shfl_xor(mj, 4));
            mj = fmaxf(mj, __shfl_xor(mj, 8));
            mjr[j] = mj;
            dm = fmaxf(dm, mj - mrow[j]);
        }
        // T13 defer-max: only rescale when some row's max grew by > 8 (log2)
        if (__any(dm > 8.0f)) {
#pragma unroll
            for (int j = 0; j < 4; j++) {
                float mn = fmaxf(mrow[j], mjr[j]);
                float sc = exp2f(mrow[j] - mn);
                mrow[j] = mn;
                lrow[j] *= sc;
#pragma unroll
                for (int n = 0; n < 4; n++) o[n][j] *= sc;
            }
        }
        float psum[4] = {0.f, 0.f, 0.f, 0.f};
#pragma unroll
        for (int n = 0; n < 4; n++)
#pragma unroll
            for (int j = 0; j < 4; j++) {
                float pv = exp2f(s[n][j] - mrow[j]);
                s[n][j] = pv;
                psum[j] += pv;
            }
#pragma unroll
        for (int j = 0; j < 4; j++) {
            psum[j] += __shfl_xor(psum[j], 1);
            psum[j] += __shfl_xor(psum[j], 2);
            psum[j] += __shfl_xor(psum[j], 4);
            psum[j] += __shfl_xor(psum[j], 8);
            lrow[j] += psum[j];
        }

        // P -> LDS (per-wave) -> A-frags
#pragma unroll
        for (int n = 0; n < 4; n++)
#pragma unroll
            for (int j = 0; j < 4; j++)
                Psm[wid][(lane >> 4) * 4 + j][n * 16 + (lane & 15)] = __float2bfloat16(s[n][j]);

        bf16x8 pa[2];
#pragma unroll
        for (int kk = 0; kk < 2; kk++)
            pa[kk] = *(const bf16x8*)&Psm[wid][lane & 15][kk * 32 + (lane >> 4) * 8];

#pragma unroll
        for (int n = 0; n < 4; n++) {
            bf16x8 v0 = *(const bf16x8*)&Vsm[n * 16 + (lane & 15)][(lane >> 4) * 8];
            bf16x8 v1 = *(const bf16x8*)&Vsm[n * 16 + (lane & 15)][32 + (lane >> 4) * 8];
            o[n] = __builtin_amdgcn_mfma_f32_16x16x32_bf16(pa[0], v0, o[n], 0, 0, 0);
            o[n] = __builtin_amdgcn_mfma_f32_16x16x32_bf16(pa[1], v1, o[n], 0, 0, 0);
        }
    }

    int b = bh >> 4, h = bh & 15;
#pragma unroll
    for (int j = 0; j < 4; j++) {
        float inv = 1.0f / lrow[j];
        int t = q0 + (lane >> 4) * 4 + j;
#pragma unroll
        for (int n = 0; n < 4; n++) {
            int c = h * 64 + n * 16 + (lane & 15);
            Y[((size_t)b * T_ + t) * D_ + c] = __float2bfloat16(o[n][j] * inv);
        }
    }
}

// ---------------------------------------------------------------------------
extern "C" void kernel_launch(void* const* d_in, const int* in_sizes, int n_in,
                              void* d_out, int out_size, void* d_ws, size_t ws_size,
                              hipStream_t stream) {
    const float* inputs = (const float*)d_in[0];
    // d_in[1] cond, d_in[2] attention_mask: unused by reference path
    const float* ln1_g = (const float*)d_in[3];
    const float* ln1_b = (const float*)d_in[4];
    const float* ln2_g = (const float*)d_in[5];
    const float* ln2_b = (const float*)d_in[6];
    const float* w_qkv = (const float*)d_in[7];
    const float* w_out = (const float*)d_in[8];
    const float* b_out = (const float*)d_in[9];
    const float* w1    = (const float*)d_in[10];
    const float* b1    = (const float*)d_in[11];
    const float* w2    = (const float*)d_in[12];
    const float* b2    = (const float*)d_in[13];

    char* p = (char*)d_ws;
    auto alloc = [&](size_t bytes) {
        void* r = (void*)p;
        p += (bytes + 255) & ~(size_t)255;
        return r;
    };
    bf16* x1     = (bf16*)alloc((size_t)ROWS * D_ * 2);
    bf16* wqkv_t = (bf16*)alloc((size_t)3 * D_ * D_ * 2);
    bf16* wout_t = (bf16*)alloc((size_t)D_ * D_ * 2);
    bf16* w1_t   = (bf16*)alloc((size_t)MLP_ * D_ * 2);
    bf16* w2_t   = (bf16*)alloc((size_t)D_ * MLP_ * 2);
    bf16* qkv    = (bf16*)alloc((size_t)3 * BHTD * 2);
    bf16* vt     = (bf16*)alloc((size_t)BHTD * 2);
    bf16* y      = (bf16*)alloc((size_t)ROWS * D_ * 2);
    float* x2    = (float*)alloc((size_t)ROWS * D_ * 4);
    bf16* h2     = (bf16*)alloc((size_t)ROWS * D_ * 2);
    bf16* act    = (bf16*)alloc((size_t)ROWS * MLP_ * 2);

    dim3 tb(32, 8);
    wtrans_kernel<<<dim3(3 * D_ / 32, D_ / 32), tb, 0, stream>>>(w_qkv, wqkv_t, D_, 3 * D_);
    wtrans_kernel<<<dim3(D_ / 32, D_ / 32), tb, 0, stream>>>(w_out, wout_t, D_, D_);
    wtrans_kernel<<<dim3(MLP_ / 32, D_ / 32), tb, 0, stream>>>(w1, w1_t, D_, MLP_);
    wtrans_kernel<<<dim3(D_ / 32, MLP_ / 32), tb, 0, stream>>>(w2, w2_t, MLP_, D_);

    ln_kernel<<<ROWS, 256, 0, stream>>>(inputs, ln1_g, ln1_b, x1);

    gemm_bt<0, 128><<<dim3(3 * D_ / 128, ROWS / 128), 256, 0, stream>>>(
        x1, wqkv_t, 3 * D_, D_, nullptr, nullptr, (void*)qkv);

    transpose_v_kernel<<<dim3(T_ / 32, 2, 32), tb, 0, stream>>>(qkv + 2 * BHTD, vt);

    attn_kernel<<<dim3(T_ / 128, 32), 512, 0, stream>>>(qkv, qkv + BHTD, vt, y);

    gemm_bt<1, 64><<<dim3(D_ / 128, ROWS / 64), 256, 0, stream>>>(
        y, wout_t, D_, D_, b_out, inputs, (void*)x2);

    ln_kernel<<<ROWS, 256, 0, stream>>>(x2, ln2_g, ln2_b, h2);

    gemm_bt<2, 128><<<dim3(MLP_ / 128, ROWS / 128), 256, 0, stream>>>(
        h2, w1_t, MLP_, D_, b1, nullptr, (void*)act);

    gemm_bt<1, 64><<<dim3(D_ / 128, ROWS / 64), 256, 0, stream>>>(
        act, w2_t, D_, MLP_, b2, x2, d_out);
}

// Round 8
// 451.453 us; speedup vs baseline: 1.2113x; 1.0967x over previous
//
#include <hip/hip_runtime.h>
#include <hip/hip_bf16.h>
#include <math.h>

using bf16 = __hip_bfloat16;
typedef __attribute__((ext_vector_type(8))) short bf16x8;
typedef __attribute__((ext_vector_type(4))) float f32x4;

#define B_   2
#define T_   2048
#define D_   1024
#define NH_  16
#define DH_  64
#define MLP_ 4096
#define ROWS (B_ * T_)                 // 4096
#define BHTD ((size_t)32 * 2048 * 64)  // one of Q/K/V, elements
#define SCL 0.18033688011112042f       // 0.125 * log2(e) — exp2-domain scores

// async global->LDS, 16B per lane (dest must be linear: wave base + lane*16)
__device__ __forceinline__ void gload_lds16(const void* g, void* l) {
    __builtin_amdgcn_global_load_lds(
        (const __attribute__((address_space(1))) unsigned int*)g,
        (__attribute__((address_space(3))) unsigned int*)l, 16, 0, 0);
}

__device__ __forceinline__ unsigned pk_bf16(float a, float b) {
    unsigned lo = __bfloat16_as_ushort(__float2bfloat16(a));
    unsigned hi = __bfloat16_as_ushort(__float2bfloat16(b));
    return lo | (hi << 16);
}

// ---------------- weight transpose-convert: W[K][N] f32 -> Wt[N][K] bf16 ----
__global__ void wtrans_kernel(const float* __restrict__ W, bf16* __restrict__ Wt,
                              int K, int N) {
    __shared__ float tile[32][33];
    int n0 = blockIdx.x * 32, k0 = blockIdx.y * 32;
    int tx = threadIdx.x, ty = threadIdx.y;  // 32 x 8
#pragma unroll
    for (int i = 0; i < 32; i += 8)
        tile[ty + i][tx] = W[(size_t)(k0 + ty + i) * N + n0 + tx];
    __syncthreads();
#pragma unroll
    for (int i = 0; i < 32; i += 8)
        Wt[(size_t)(n0 + ty + i) * K + k0 + tx] = __float2bfloat16(tile[tx][ty + i]);
}

// ---------------- per-head V transpose: V[bh][t][64] -> Vt[bh][64][t] -------
__global__ void transpose_v_kernel(const bf16* __restrict__ V, bf16* __restrict__ Vt) {
    __shared__ bf16 tile[32][33];
    int bh = blockIdx.z;
    int t0 = blockIdx.x * 32;
    int d0 = blockIdx.y * 32;
    int tx = threadIdx.x, ty = threadIdx.y;  // 32 x 8
    const bf16* src = V + (size_t)bh * T_ * 64;
    bf16* dst = Vt + (size_t)bh * 64 * T_;
#pragma unroll
    for (int i = 0; i < 32; i += 8)
        tile[ty + i][tx] = src[(size_t)(t0 + ty + i) * 64 + d0 + tx];
    __syncthreads();
#pragma unroll
    for (int i = 0; i < 32; i += 8)
        dst[(size_t)(d0 + ty + i) * T_ + t0 + tx] = tile[tx][ty + i];
}

// ---------------- LayerNorm (row of 1024) f32 -> bf16 ----------------------
__global__ void ln_kernel(const float* __restrict__ x, const float* __restrict__ g,
                          const float* __restrict__ bta, bf16* __restrict__ out) {
    int row = blockIdx.x;
    int t = threadIdx.x;  // 256 threads * float4
    float4 v = ((const float4*)(x + (size_t)row * D_))[t];
    float s1 = v.x + v.y + v.z + v.w;
    float s2 = v.x * v.x + v.y * v.y + v.z * v.z + v.w * v.w;
#pragma unroll
    for (int m = 1; m < 64; m <<= 1) {
        s1 += __shfl_xor(s1, m);
        s2 += __shfl_xor(s2, m);
    }
    __shared__ float red[8];
    int wid = t >> 6, lane = t & 63;
    if (lane == 0) { red[wid] = s1; red[4 + wid] = s2; }
    __syncthreads();
    s1 = red[0] + red[1] + red[2] + red[3];
    s2 = red[4] + red[5] + red[6] + red[7];
    float mu = s1 * (1.0f / D_);
    float var = s2 * (1.0f / D_) - mu * mu;
    float rs = rsqrtf(var + 1e-5f);
    float4 gv = ((const float4*)g)[t];
    float4 bv = ((const float4*)bta)[t];
    bf16* o = out + (size_t)row * D_ + t * 4;
    o[0] = __float2bfloat16((v.x - mu) * rs * gv.x + bv.x);
    o[1] = __float2bfloat16((v.y - mu) * rs * gv.y + bv.y);
    o[2] = __float2bfloat16((v.z - mu) * rs * gv.z + bv.z);
    o[3] = __float2bfloat16((v.w - mu) * rs * gv.w + bv.w);
}

// ---------------- GEMM: C[M][N] = A[M][K](bf16) @ Bt[N][K](bf16)^T ----------
// m97 structure: BMx128 tile, BK=64, linear LDS + global_load_lds width=16.
// EPI 0: qkv head-scatter (bf16), Q pre-scaled by SCL.
// EPI 1: +bias +resid -> f32.  EPI 2: gelu(+bias) -> bf16.
template <int EPI, int BM>
__global__ __launch_bounds__(256) void gemm_bt(const bf16* __restrict__ A,
                                               const bf16* __restrict__ Bt,
                                               int N, int K,
                                               const float* __restrict__ bias,
                                               const float* __restrict__ resid,
                                               void* __restrict__ out) {
    constexpr int MF = BM / 32;                   // m-frags per wave
    __shared__ __align__(16) bf16 Asm[BM * 64];   // linear [row][64]
    __shared__ __align__(16) bf16 Bsm[128 * 64];
    int tid = threadIdx.x;
    // XCD swizzle: contiguous chunks of the linear wg id per XCD (nwg % 8 == 0)
    int nwg = gridDim.x * gridDim.y;
    int wg = blockIdx.y * gridDim.x + blockIdx.x;
    int swz = (wg & 7) * (nwg >> 3) + (wg >> 3);
    int bm = (swz / gridDim.x) * BM;
    int bn = (swz % gridDim.x) * 128;
    int wid = tid >> 6, lane = tid & 63;
    int wr = wid >> 1, wc = wid & 1;
    f32x4 acc[MF][4];
#pragma unroll
    for (int m = 0; m < MF; m++)
#pragma unroll
        for (int n = 0; n < 4; n++) acc[m][n] = (f32x4){0.f, 0.f, 0.f, 0.f};

    for (int k0 = 0; k0 < K; k0 += 64) {
        __syncthreads();
#pragma unroll
        for (int i = 0; i < BM * 8 / 256; i++) {
            int c = tid + i * 256;
            int row = c >> 3, col8 = (c & 7) * 8;
            gload_lds16(&A[(size_t)(bm + row) * K + k0 + col8], &Asm[c * 8]);
        }
#pragma unroll
        for (int i = 0; i < 4; i++) {
            int c = tid + i * 256;
            int row = c >> 3, col8 = (c & 7) * 8;
            gload_lds16(&Bt[(size_t)(bn + row) * K + k0 + col8], &Bsm[c * 8]);
        }
        __syncthreads();
#pragma unroll
        for (int kk = 0; kk < 2; kk++) {
            bf16x8 af[MF], bfr[4];
#pragma unroll
            for (int m = 0; m < MF; m++)
                af[m] = *(const bf16x8*)&Asm[(wr * (BM / 2) + m * 16 + (lane & 15)) * 64 + kk * 32 + (lane >> 4) * 8];
#pragma unroll
            for (int n = 0; n < 4; n++)
                bfr[n] = *(const bf16x8*)&Bsm[(wc * 64 + n * 16 + (lane & 15)) * 64 + kk * 32 + (lane >> 4) * 8];
#pragma unroll
            for (int m = 0; m < MF; m++)
#pragma unroll
                for (int n = 0; n < 4; n++)
                    acc[m][n] = __builtin_amdgcn_mfma_f32_16x16x32_bf16(af[m], bfr[n], acc[m][n], 0, 0, 0);
        }
    }
    int r0 = bm + wr * (BM / 2);
    int c0 = bn + wc * 64;
#pragma unroll
    for (int m = 0; m < MF; m++) {
#pragma unroll
        for (int n = 0; n < 4; n++) {
#pragma unroll
            for (int j = 0; j < 4; j++) {
                int r = r0 + m * 16 + (lane >> 4) * 4 + j;
                int c = c0 + n * 16 + (lane & 15);
                float v = acc[m][n][j];
                if constexpr (EPI == 0) {
                    int which = c >> 10, d = c & 1023;
                    int h = d >> 6, dh = d & 63;
                    int b = r >> 11, t = r & 2047;
                    if (which == 0) v *= SCL;   // pre-scale Q for exp2-domain attn
                    ((bf16*)out)[(((size_t)which * 32 + b * 16 + h) * 2048 + t) * 64 + dh] =
                        __float2bfloat16(v);
                } else if constexpr (EPI == 1) {
                    ((float*)out)[(size_t)r * N + c] = v + bias[c] + resid[(size_t)r * N + c];
                } else {
                    float u = v + bias[c];
                    float ge = 0.5f * u * (1.0f + erff(u * 0.70710678118f));
                    ((bf16*)out)[(size_t)r * N + c] = __float2bfloat16(ge);
                }
            }
        }
    }
}

// ---------------- flash attention: 8 waves, 128 q-rows/block, KVBLK=64 ------
// Swapped QK^T: s = mfma(K_frag, Q_frag) -> lane holds 16 keys for ONE q-row
// (q = lane&15, keys = n*16 + (lane>>4)*4 + j). Row reduce = in-lane + 2 shfl.
__global__ __launch_bounds__(512) void attn_kernel(const bf16* __restrict__ Q,
                                                   const bf16* __restrict__ Kt,
                                                   const bf16* __restrict__ Vt,
                                                   bf16* __restrict__ Y) {
    __shared__ __align__(16) bf16 Ksm[64][72];
    __shared__ __align__(16) bf16 Vsm[64][72];       // Vsm[dh][key]
    __shared__ __align__(16) bf16 Psm[8][16][72];    // per-wave P[q][key]
    int tid = threadIdx.x;
    int wid = tid >> 6, lane = tid & 63;
    int bh = blockIdx.y;
    int q0 = blockIdx.x * 128 + wid * 16;
    const bf16* Qb = Q + (size_t)bh * T_ * 64;
    const bf16* Kb = Kt + (size_t)bh * T_ * 64;
    const bf16* Vb = Vt + (size_t)bh * 64 * T_;

    bf16x8 aq[2];   // used as B operand (cols = q)
#pragma unroll
    for (int kk = 0; kk < 2; kk++)
        aq[kk] = *(const bf16x8*)&Qb[(size_t)(q0 + (lane & 15)) * 64 + kk * 32 + (lane >> 4) * 8];

    float mrow = -1e30f, lrow = 0.f;
    f32x4 o[4];
#pragma unroll
    for (int n = 0; n < 4; n++) o[n] = (f32x4){0.f, 0.f, 0.f, 0.f};

    for (int kt = 0; kt < T_ / 64; kt++) {
        __syncthreads();
        {
            int row = tid >> 3, col8 = (tid & 7) * 8;
            *(uint4*)&Ksm[row][col8] = *(const uint4*)&Kb[(size_t)(kt * 64 + row) * 64 + col8];
            *(uint4*)&Vsm[row][col8] = *(const uint4*)&Vb[(size_t)row * T_ + kt * 64 + col8];
        }
        __syncthreads();

        f32x4 s[4];
#pragma unroll
        for (int n = 0; n < 4; n++) {
            bf16x8 k0f = *(const bf16x8*)&Ksm[n * 16 + (lane & 15)][(lane >> 4) * 8];
            bf16x8 k1f = *(const bf16x8*)&Ksm[n * 16 + (lane & 15)][32 + (lane >> 4) * 8];
            s[n] = __builtin_amdgcn_mfma_f32_16x16x32_bf16(k0f, aq[0], (f32x4){0.f, 0.f, 0.f, 0.f}, 0, 0, 0);
            s[n] = __builtin_amdgcn_mfma_f32_16x16x32_bf16(k1f, aq[1], s[n], 0, 0, 0);
        }

        // in-lane max over 16 keys, then combine the 4 lane-groups
        float my = fmaxf(fmaxf(fmaxf(s[0][0], s[0][1]), fmaxf(s[0][2], s[0][3])),
                         fmaxf(fmaxf(s[1][0], s[1][1]), fmaxf(s[1][2], s[1][3])));
        float my2 = fmaxf(fmaxf(fmaxf(s[2][0], s[2][1]), fmaxf(s[2][2], s[2][3])),
                          fmaxf(fmaxf(s[3][0], s[3][1]), fmaxf(s[3][2], s[3][3])));
        my = fmaxf(my, my2);
        my = fmaxf(my, __shfl_xor(my, 16));
        my = fmaxf(my, __shfl_xor(my, 32));

        // T13 defer-max: rescale only when the running max grew by > 8 (log2)
        if (__any(my - mrow > 8.0f)) {
            float mn = fmaxf(mrow, my);
            float sc = exp2f(mrow - mn);
            mrow = mn;
            lrow *= sc;
#pragma unroll
            for (int j = 0; j < 4; j++) {
                float scj = __shfl(sc, (lane >> 4) * 4 + j);
#pragma unroll
                for (int n = 0; n < 4; n++) o[n][j] *= scj;
            }
        }

        float psum = 0.f;
#pragma unroll
        for (int n = 0; n < 4; n++)
#pragma unroll
            for (int j = 0; j < 4; j++) {
                float pv = exp2f(s[n][j] - mrow);
                s[n][j] = pv;
                psum += pv;
            }
        psum += __shfl_xor(psum, 16);
        psum += __shfl_xor(psum, 32);
        lrow += psum;

        // P -> LDS: one b64 per n (4 consecutive keys packed as bf16)
#pragma unroll
        for (int n = 0; n < 4; n++) {
            uint2 w;
            w.x = pk_bf16(s[n][0], s[n][1]);
            w.y = pk_bf16(s[n][2], s[n][3]);
            *(uint2*)&Psm[wid][lane & 15][n * 16 + (lane >> 4) * 4] = w;
        }

        bf16x8 pa[2];
#pragma unroll
        for (int kk = 0; kk < 2; kk++)
            pa[kk] = *(const bf16x8*)&Psm[wid][lane & 15][kk * 32 + (lane >> 4) * 8];

#pragma unroll
        for (int n = 0; n < 4; n++) {
            bf16x8 v0 = *(const bf16x8*)&Vsm[n * 16 + (lane & 15)][(lane >> 4) * 8];
            bf16x8 v1 = *(const bf16x8*)&Vsm[n * 16 + (lane & 15)][32 + (lane >> 4) * 8];
            o[n] = __builtin_amdgcn_mfma_f32_16x16x32_bf16(pa[0], v0, o[n], 0, 0, 0);
            o[n] = __builtin_amdgcn_mfma_f32_16x16x32_bf16(pa[1], v1, o[n], 0, 0, 0);
        }
    }

    int b = bh >> 4, h = bh & 15;
#pragma unroll
    for (int j = 0; j < 4; j++) {
        float lj = __shfl(lrow, (lane >> 4) * 4 + j);
        float inv = 1.0f / lj;
        int t = q0 + (lane >> 4) * 4 + j;
#pragma unroll
        for (int n = 0; n < 4; n++) {
            int c = h * 64 + n * 16 + (lane & 15);
            Y[((size_t)b * T_ + t) * D_ + c] = __float2bfloat16(o[n][j] * inv);
        }
    }
}

// ---------------------------------------------------------------------------
extern "C" void kernel_launch(void* const* d_in, const int* in_sizes, int n_in,
                              void* d_out, int out_size, void* d_ws, size_t ws_size,
                              hipStream_t stream) {
    const float* inputs = (const float*)d_in[0];
    // d_in[1] cond, d_in[2] attention_mask: unused by reference path
    const float* ln1_g = (const float*)d_in[3];
    const float* ln1_b = (const float*)d_in[4];
    const float* ln2_g = (const float*)d_in[5];
    const float* ln2_b = (const float*)d_in[6];
    const float* w_qkv = (const float*)d_in[7];
    const float* w_out = (const float*)d_in[8];
    const float* b_out = (const float*)d_in[9];
    const float* w1    = (const float*)d_in[10];
    const float* b1    = (const float*)d_in[11];
    const float* w2    = (const float*)d_in[12];
    const float* b2    = (const float*)d_in[13];

    char* p = (char*)d_ws;
    auto alloc = [&](size_t bytes) {
        void* r = (void*)p;
        p += (bytes + 255) & ~(size_t)255;
        return r;
    };
    bf16* x1     = (bf16*)alloc((size_t)ROWS * D_ * 2);
    bf16* wqkv_t = (bf16*)alloc((size_t)3 * D_ * D_ * 2);
    bf16* wout_t = (bf16*)alloc((size_t)D_ * D_ * 2);
    bf16* w1_t   = (bf16*)alloc((size_t)MLP_ * D_ * 2);
    bf16* w2_t   = (bf16*)alloc((size_t)D_ * MLP_ * 2);
    bf16* qkv    = (bf16*)alloc((size_t)3 * BHTD * 2);
    bf16* vt     = (bf16*)alloc((size_t)BHTD * 2);
    bf16* y      = (bf16*)alloc((size_t)ROWS * D_ * 2);
    float* x2    = (float*)alloc((size_t)ROWS * D_ * 4);
    bf16* h2     = (bf16*)alloc((size_t)ROWS * D_ * 2);
    bf16* act    = (bf16*)alloc((size_t)ROWS * MLP_ * 2);

    dim3 tb(32, 8);
    wtrans_kernel<<<dim3(3 * D_ / 32, D_ / 32), tb, 0, stream>>>(w_qkv, wqkv_t, D_, 3 * D_);
    wtrans_kernel<<<dim3(D_ / 32, D_ / 32), tb, 0, stream>>>(w_out, wout_t, D_, D_);
    wtrans_kernel<<<dim3(MLP_ / 32, D_ / 32), tb, 0, stream>>>(w1, w1_t, D_, MLP_);
    wtrans_kernel<<<dim3(D_ / 32, MLP_ / 32), tb, 0, stream>>>(w2, w2_t, MLP_, D_);

    ln_kernel<<<ROWS, 256, 0, stream>>>(inputs, ln1_g, ln1_b, x1);

    gemm_bt<0, 128><<<dim3(3 * D_ / 128, ROWS / 128), 256, 0, stream>>>(
        x1, wqkv_t, 3 * D_, D_, nullptr, nullptr, (void*)qkv);

    transpose_v_kernel<<<dim3(T_ / 32, 2, 32), tb, 0, stream>>>(qkv + 2 * BHTD, vt);

    attn_kernel<<<dim3(T_ / 128, 32), 512, 0, stream>>>(qkv, qkv + BHTD, vt, y);

    gemm_bt<1, 64><<<dim3(D_ / 128, ROWS / 64), 256, 0, stream>>>(
        y, wout_t, D_, D_, b_out, inputs, (void*)x2);

    ln_kernel<<<ROWS, 256, 0, stream>>>(x2, ln2_g, ln2_b, h2);

    gemm_bt<2, 128><<<dim3(MLP_ / 128, ROWS / 128), 256, 0, stream>>>(
        h2, w1_t, MLP_, D_, b1, nullptr, (void*)act);

    gemm_bt<1, 64><<<dim3(D_ / 128, ROWS / 64), 256, 0, stream>>>(
        act, w2_t, D_, MLP_, b2, x2, d_out);
}

// Round 10
// 425.477 us; speedup vs baseline: 1.2852x; 1.0610x over previous
//
#include <hip/hip_runtime.h>
#include <hip/hip_bf16.h>
#include <math.h>

using bf16 = __hip_bfloat16;
typedef __attribute__((ext_vector_type(8))) short bf16x8;
typedef __attribute__((ext_vector_type(4))) float f32x4;

#define B_   2
#define T_   2048
#define D_   1024
#define NH_  16
#define DH_  64
#define MLP_ 4096
#define ROWS (B_ * T_)                 // 4096
#define BHTD ((size_t)32 * 2048 * 64)  // one of Q/K/V, elements
#define SCL 0.18033688011112042f       // 0.125 * log2(e) — exp2-domain scores

// async global->LDS, 16B per lane (dest must be linear: wave base + lane*16)
__device__ __forceinline__ void gload_lds16(const void* g, void* l) {
    __builtin_amdgcn_global_load_lds(
        (const __attribute__((address_space(1))) unsigned int*)g,
        (__attribute__((address_space(3))) unsigned int*)l, 16, 0, 0);
}

__device__ __forceinline__ unsigned pk_bf16(float a, float b) {
    unsigned lo = __bfloat16_as_ushort(__float2bfloat16(a));
    unsigned hi = __bfloat16_as_ushort(__float2bfloat16(b));
    return lo | (hi << 16);
}

// ---------------- weight transpose-convert: W[K][N] f32 -> Wt[N][K] bf16 ----
__global__ void wtrans_kernel(const float* __restrict__ W, bf16* __restrict__ Wt,
                              int K, int N) {
    __shared__ float tile[32][33];
    int n0 = blockIdx.x * 32, k0 = blockIdx.y * 32;
    int tx = threadIdx.x, ty = threadIdx.y;  // 32 x 8
#pragma unroll
    for (int i = 0; i < 32; i += 8)
        tile[ty + i][tx] = W[(size_t)(k0 + ty + i) * N + n0 + tx];
    __syncthreads();
#pragma unroll
    for (int i = 0; i < 32; i += 8)
        Wt[(size_t)(n0 + ty + i) * K + k0 + tx] = __float2bfloat16(tile[tx][ty + i]);
}

// ---------------- per-head V transpose: V[bh][t][64] -> Vt[bh][64][t] -------
__global__ void transpose_v_kernel(const bf16* __restrict__ V, bf16* __restrict__ Vt) {
    __shared__ bf16 tile[32][33];
    int bh = blockIdx.z;
    int t0 = blockIdx.x * 32;
    int d0 = blockIdx.y * 32;
    int tx = threadIdx.x, ty = threadIdx.y;  // 32 x 8
    const bf16* src = V + (size_t)bh * T_ * 64;
    bf16* dst = Vt + (size_t)bh * 64 * T_;
#pragma unroll
    for (int i = 0; i < 32; i += 8)
        tile[ty + i][tx] = src[(size_t)(t0 + ty + i) * 64 + d0 + tx];
    __syncthreads();
#pragma unroll
    for (int i = 0; i < 32; i += 8)
        dst[(size_t)(d0 + ty + i) * T_ + t0 + tx] = tile[tx][ty + i];
}

// ---------------- LayerNorm (row of 1024) f32 -> bf16 ----------------------
__global__ void ln_kernel(const float* __restrict__ x, const float* __restrict__ g,
                          const float* __restrict__ bta, bf16* __restrict__ out) {
    int row = blockIdx.x;
    int t = threadIdx.x;  // 256 threads * float4
    float4 v = ((const float4*)(x + (size_t)row * D_))[t];
    float s1 = v.x + v.y + v.z + v.w;
    float s2 = v.x * v.x + v.y * v.y + v.z * v.z + v.w * v.w;
#pragma unroll
    for (int m = 1; m < 64; m <<= 1) {
        s1 += __shfl_xor(s1, m);
        s2 += __shfl_xor(s2, m);
    }
    __shared__ float red[8];
    int wid = t >> 6, lane = t & 63;
    if (lane == 0) { red[wid] = s1; red[4 + wid] = s2; }
    __syncthreads();
    s1 = red[0] + red[1] + red[2] + red[3];
    s2 = red[4] + red[5] + red[6] + red[7];
    float mu = s1 * (1.0f / D_);
    float var = s2 * (1.0f / D_) - mu * mu;
    float rs = rsqrtf(var + 1e-5f);
    float4 gv = ((const float4*)g)[t];
    float4 bv = ((const float4*)bta)[t];
    bf16* o = out + (size_t)row * D_ + t * 4;
    o[0] = __float2bfloat16((v.x - mu) * rs * gv.x + bv.x);
    o[1] = __float2bfloat16((v.y - mu) * rs * gv.y + bv.y);
    o[2] = __float2bfloat16((v.z - mu) * rs * gv.z + bv.z);
    o[3] = __float2bfloat16((v.w - mu) * rs * gv.w + bv.w);
}

// ---------------- GEMM: C[M][N] = A[M][K](bf16) @ Bt[N][K](bf16)^T ----------
// m97 structure + T2 XOR-swizzle (rule 21: linear gload_lds dest, inverse-
// swizzled GLOBAL source, same XOR on ds_read). Breaks the 16-way bank
// conflict of linear [row][64] rows (stride 128B == 0 mod 32 banks).
// EPI 0: qkv head-scatter (bf16), Q pre-scaled by SCL.
// EPI 1: +bias +resid -> f32.  EPI 2: gelu(+bias) -> bf16.
template <int EPI, int BM>
__global__ __launch_bounds__(256) void gemm_bt(const bf16* __restrict__ A,
                                               const bf16* __restrict__ Bt,
                                               int N, int K,
                                               const float* __restrict__ bias,
                                               const float* __restrict__ resid,
                                               void* __restrict__ out) {
    constexpr int MF = BM / 32;                   // m-frags per wave
    __shared__ __align__(16) bf16 Asm[BM * 64];   // linear [row][64], swizzled content
    __shared__ __align__(16) bf16 Bsm[128 * 64];
    int tid = threadIdx.x;
    // XCD swizzle: contiguous chunks of the linear wg id per XCD (nwg % 8 == 0)
    int nwg = gridDim.x * gridDim.y;
    int wg = blockIdx.y * gridDim.x + blockIdx.x;
    int swz = (wg & 7) * (nwg >> 3) + (wg >> 3);
    int bm = (swz / gridDim.x) * BM;
    int bn = (swz % gridDim.x) * 128;
    int wid = tid >> 6, lane = tid & 63;
    int wr = wid >> 1, wc = wid & 1;
    f32x4 acc[MF][4];
#pragma unroll
    for (int m = 0; m < MF; m++)
#pragma unroll
        for (int n = 0; n < 4; n++) acc[m][n] = (f32x4){0.f, 0.f, 0.f, 0.f};

    for (int k0 = 0; k0 < K; k0 += 64) {
        __syncthreads();
#pragma unroll
        for (int i = 0; i < BM * 8 / 256; i++) {
            int c = tid + i * 256;
            int row = c >> 3;
            int sw = ((c & 7) ^ (row & 7)) * 8;   // inverse-swizzled source col
            gload_lds16(&A[(size_t)(bm + row) * K + k0 + sw], &Asm[c * 8]);
        }
#pragma unroll
        for (int i = 0; i < 4; i++) {
            int c = tid + i * 256;
            int row = c >> 3;
            int sw = ((c & 7) ^ (row & 7)) * 8;
            gload_lds16(&Bt[(size_t)(bn + row) * K + k0 + sw], &Bsm[c * 8]);
        }
        __syncthreads();
#pragma unroll
        for (int kk = 0; kk < 2; kk++) {
            int cc = kk * 4 + (lane >> 4);        // logical 16B-chunk index
            bf16x8 af[MF], bfr[4];
#pragma unroll
            for (int m = 0; m < MF; m++) {
                int ra = wr * (BM / 2) + m * 16 + (lane & 15);
                af[m] = *(const bf16x8*)&Asm[ra * 64 + ((cc ^ (ra & 7)) * 8)];
            }
#pragma unroll
            for (int n = 0; n < 4; n++) {
                int rb = wc * 64 + n * 16 + (lane & 15);
                bfr[n] = *(const bf16x8*)&Bsm[rb * 64 + ((cc ^ (rb & 7)) * 8)];
            }
#pragma unroll
            for (int m = 0; m < MF; m++)
#pragma unroll
                for (int n = 0; n < 4; n++)
                    acc[m][n] = __builtin_amdgcn_mfma_f32_16x16x32_bf16(af[m], bfr[n], acc[m][n], 0, 0, 0);
        }
    }
    int r0 = bm + wr * (BM / 2);
    int c0 = bn + wc * 64;
#pragma unroll
    for (int m = 0; m < MF; m++) {
#pragma unroll
        for (int n = 0; n < 4; n++) {
#pragma unroll
            for (int j = 0; j < 4; j++) {
                int r = r0 + m * 16 + (lane >> 4) * 4 + j;
                int c = c0 + n * 16 + (lane & 15);
                float v = acc[m][n][j];
                if constexpr (EPI == 0) {
                    int which = c >> 10, d = c & 1023;
                    int h = d >> 6, dh = d & 63;
                    int b = r >> 11, t = r & 2047;
                    if (which == 0) v *= SCL;   // pre-scale Q for exp2-domain attn
                    ((bf16*)out)[(((size_t)which * 32 + b * 16 + h) * 2048 + t) * 64 + dh] =
                        __float2bfloat16(v);
                } else if constexpr (EPI == 1) {
                    ((float*)out)[(size_t)r * N + c] = v + bias[c] + resid[(size_t)r * N + c];
                } else {
                    float u = v + bias[c];
                    float ge = 0.5f * u * (1.0f + erff(u * 0.70710678118f));
                    ((bf16*)out)[(size_t)r * N + c] = __float2bfloat16(ge);
                }
            }
        }
    }
}

// ---------------- flash attention: 8 waves, 128 q-rows/block, KVBLK=64 ------
// Swapped QK^T: s = mfma(K_frag, Q_frag) -> lane holds 16 keys for ONE q-row
// (q = lane&15, keys = n*16 + (lane>>4)*4 + j). Row reduce = in-lane + 2 shfl.
// T5: setprio(1) around MFMA clusters (waves at independent phases).
__global__ __launch_bounds__(512) void attn_kernel(const bf16* __restrict__ Q,
                                                   const bf16* __restrict__ Kt,
                                                   const bf16* __restrict__ Vt,
                                                   bf16* __restrict__ Y) {
    __shared__ __align__(16) bf16 Ksm[64][72];
    __shared__ __align__(16) bf16 Vsm[64][72];       // Vsm[dh][key]
    __shared__ __align__(16) bf16 Psm[8][16][72];    // per-wave P[q][key]
    int tid = threadIdx.x;
    int wid = tid >> 6, lane = tid & 63;
    int bh = blockIdx.y;
    int q0 = blockIdx.x * 128 + wid * 16;
    const bf16* Qb = Q + (size_t)bh * T_ * 64;
    const bf16* Kb = Kt + (size_t)bh * T_ * 64;
    const bf16* Vb = Vt + (size_t)bh * 64 * T_;

    bf16x8 aq[2];   // used as B operand (cols = q)
#pragma unroll
    for (int kk = 0; kk < 2; kk++)
        aq[kk] = *(const bf16x8*)&Qb[(size_t)(q0 + (lane & 15)) * 64 + kk * 32 + (lane >> 4) * 8];

    float mrow = -1e30f, lrow = 0.f;
    f32x4 o[4];
#pragma unroll
    for (int n = 0; n < 4; n++) o[n] = (f32x4){0.f, 0.f, 0.f, 0.f};

    for (int kt = 0; kt < T_ / 64; kt++) {
        __syncthreads();
        {
            int row = tid >> 3, col8 = (tid & 7) * 8;
            *(uint4*)&Ksm[row][col8] = *(const uint4*)&Kb[(size_t)(kt * 64 + row) * 64 + col8];
            *(uint4*)&Vsm[row][col8] = *(const uint4*)&Vb[(size_t)row * T_ + kt * 64 + col8];
        }
        __syncthreads();

        f32x4 s[4];
        __builtin_amdgcn_s_setprio(1);
#pragma unroll
        for (int n = 0; n < 4; n++) {
            bf16x8 k0f = *(const bf16x8*)&Ksm[n * 16 + (lane & 15)][(lane >> 4) * 8];
            bf16x8 k1f = *(const bf16x8*)&Ksm[n * 16 + (lane & 15)][32 + (lane >> 4) * 8];
            s[n] = __builtin_amdgcn_mfma_f32_16x16x32_bf16(k0f, aq[0], (f32x4){0.f, 0.f, 0.f, 0.f}, 0, 0, 0);
            s[n] = __builtin_amdgcn_mfma_f32_16x16x32_bf16(k1f, aq[1], s[n], 0, 0, 0);
        }
        __builtin_amdgcn_s_setprio(0);

        // in-lane max over 16 keys, then combine the 4 lane-groups
        float my = fmaxf(fmaxf(fmaxf(s[0][0], s[0][1]), fmaxf(s[0][2], s[0][3])),
                         fmaxf(fmaxf(s[1][0], s[1][1]), fmaxf(s[1][2], s[1][3])));
        float my2 = fmaxf(fmaxf(fmaxf(s[2][0], s[2][1]), fmaxf(s[2][2], s[2][3])),
                          fmaxf(fmaxf(s[3][0], s[3][1]), fmaxf(s[3][2], s[3][3])));
        my = fmaxf(my, my2);
        my = fmaxf(my, __shfl_xor(my, 16));
        my = fmaxf(my, __shfl_xor(my, 32));

        // T13 defer-max: rescale only when the running max grew by > 8 (log2)
        if (__any(my - mrow > 8.0f)) {
            float mn = fmaxf(mrow, my);
            float sc = exp2f(mrow - mn);
            mrow = mn;
            lrow *= sc;
#pragma unroll
            for (int j = 0; j < 4; j++) {
                float scj = __shfl(sc, (lane >> 4) * 4 + j);
#pragma unroll
                for (int n = 0; n < 4; n++) o[n][j] *= scj;
            }
        }

        float psum = 0.f;
#pragma unroll
        for (int n = 0; n < 4; n++)
#pragma unroll
            for (int j = 0; j < 4; j++) {
                float pv = exp2f(s[n][j] - mrow);
                s[n][j] = pv;
                psum += pv;
            }
        psum += __shfl_xor(psum, 16);
        psum += __shfl_xor(psum, 32);
        lrow += psum;

        // P -> LDS: one b64 per n (4 consecutive keys packed as bf16)
#pragma unroll
        for (int n = 0; n < 4; n++) {
            uint2 w;
            w.x = pk_bf16(s[n][0], s[n][1]);
            w.y = pk_bf16(s[n][2], s[n][3]);
            *(uint2*)&Psm[wid][lane & 15][n * 16 + (lane >> 4) * 4] = w;
        }

        bf16x8 pa[2];
#pragma unroll
        for (int kk = 0; kk < 2; kk++)
            pa[kk] = *(const bf16x8*)&Psm[wid][lane & 15][kk * 32 + (lane >> 4) * 8];

        __builtin_amdgcn_s_setprio(1);
#pragma unroll
        for (int n = 0; n < 4; n++) {
            bf16x8 v0 = *(const bf16x8*)&Vsm[n * 16 + (lane & 15)][(lane >> 4) * 8];
            bf16x8 v1 = *(const bf16x8*)&Vsm[n * 16 + (lane & 15)][32 + (lane >> 4) * 8];
            o[n] = __builtin_amdgcn_mfma_f32_16x16x32_bf16(pa[0], v0, o[n], 0, 0, 0);
            o[n] = __builtin_amdgcn_mfma_f32_16x16x32_bf16(pa[1], v1, o[n], 0, 0, 0);
        }
        __builtin_amdgcn_s_setprio(0);
    }

    int b = bh >> 4, h = bh & 15;
#pragma unroll
    for (int j = 0; j < 4; j++) {
        float lj = __shfl(lrow, (lane >> 4) * 4 + j);
        float inv = 1.0f / lj;
        int t = q0 + (lane >> 4) * 4 + j;
#pragma unroll
        for (int n = 0; n < 4; n++) {
            int c = h * 64 + n * 16 + (lane & 15);
            Y[((size_t)b * T_ + t) * D_ + c] = __float2bfloat16(o[n][j] * inv);
        }
    }
}

// ---------------------------------------------------------------------------
extern "C" void kernel_launch(void* const* d_in, const int* in_sizes, int n_in,
                              void* d_out, int out_size, void* d_ws, size_t ws_size,
                              hipStream_t stream) {
    const float* inputs = (const float*)d_in[0];
    // d_in[1] cond, d_in[2] attention_mask: unused by reference path
    const float* ln1_g = (const float*)d_in[3];
    const float* ln1_b = (const float*)d_in[4];
    const float* ln2_g = (const float*)d_in[5];
    const float* ln2_b = (const float*)d_in[6];
    const float* w_qkv = (const float*)d_in[7];
    const float* w_out = (const float*)d_in[8];
    const float* b_out = (const float*)d_in[9];
    const float* w1    = (const float*)d_in[10];
    const float* b1    = (const float*)d_in[11];
    const float* w2    = (const float*)d_in[12];
    const float* b2    = (const float*)d_in[13];

    char* p = (char*)d_ws;
    auto alloc = [&](size_t bytes) {
        void* r = (void*)p;
        p += (bytes + 255) & ~(size_t)255;
        return r;
    };
    bf16* x1     = (bf16*)alloc((size_t)ROWS * D_ * 2);
    bf16* wqkv_t = (bf16*)alloc((size_t)3 * D_ * D_ * 2);
    bf16* wout_t = (bf16*)alloc((size_t)D_ * D_ * 2);
    bf16* w1_t   = (bf16*)alloc((size_t)MLP_ * D_ * 2);
    bf16* w2_t   = (bf16*)alloc((size_t)D_ * MLP_ * 2);
    bf16* qkv    = (bf16*)alloc((size_t)3 * BHTD * 2);
    bf16* vt     = (bf16*)alloc((size_t)BHTD * 2);
    bf16* y      = (bf16*)alloc((size_t)ROWS * D_ * 2);
    float* x2    = (float*)alloc((size_t)ROWS * D_ * 4);
    bf16* h2     = (bf16*)alloc((size_t)ROWS * D_ * 2);
    bf16* act    = (bf16*)alloc((size_t)ROWS * MLP_ * 2);

    dim3 tb(32, 8);
    wtrans_kernel<<<dim3(3 * D_ / 32, D_ / 32), tb, 0, stream>>>(w_qkv, wqkv_t, D_, 3 * D_);
    wtrans_kernel<<<dim3(D_ / 32, D_ / 32), tb, 0, stream>>>(w_out, wout_t, D_, D_);
    wtrans_kernel<<<dim3(MLP_ / 32, D_ / 32), tb, 0, stream>>>(w1, w1_t, D_, MLP_);
    wtrans_kernel<<<dim3(D_ / 32, MLP_ / 32), tb, 0, stream>>>(w2, w2_t, MLP_, D_);

    ln_kernel<<<ROWS, 256, 0, stream>>>(inputs, ln1_g, ln1_b, x1);

    gemm_bt<0, 128><<<dim3(3 * D_ / 128, ROWS / 128), 256, 0, stream>>>(
        x1, wqkv_t, 3 * D_, D_, nullptr, nullptr, (void*)qkv);

    transpose_v_kernel<<<dim3(T_ / 32, 2, 32), tb, 0, stream>>>(qkv + 2 * BHTD, vt);

    attn_kernel<<<dim3(T_ / 128, 32), 512, 0, stream>>>(qkv, qkv + BHTD, vt, y);

    gemm_bt<1, 64><<<dim3(D_ / 128, ROWS / 64), 256, 0, stream>>>(
        y, wout_t, D_, D_, b_out, inputs, (void*)x2);

    ln_kernel<<<ROWS, 256, 0, stream>>>(x2, ln2_g, ln2_b, h2);

    gemm_bt<2, 128><<<dim3(MLP_ / 128, ROWS / 128), 256, 0, stream>>>(
        h2, w1_t, MLP_, D_, b1, nullptr, (void*)act);

    gemm_bt<1, 64><<<dim3(D_ / 128, ROWS / 64), 256, 0, stream>>>(
        act, w2_t, D_, MLP_, b2, x2, d_out);
}

// Round 11
// 393.571 us; speedup vs baseline: 1.3894x; 1.0811x over previous
//
#include <hip/hip_runtime.h>
#include <hip/hip_bf16.h>
#include <math.h>

using bf16 = __hip_bfloat16;
typedef __attribute__((ext_vector_type(8))) short bf16x8;
typedef __attribute__((ext_vector_type(4))) float f32x4;

#define B_   2
#define T_   2048
#define D_   1024
#define NH_  16
#define DH_  64
#define MLP_ 4096
#define ROWS (B_ * T_)                 // 4096
#define BHTD ((size_t)32 * 2048 * 64)  // one of Q/K/V, elements
#define SCL 0.18033688011112042f       // 0.125 * log2(e) — exp2-domain scores

// async global->LDS, 16B per lane (dest must be linear: wave base + lane*16)
__device__ __forceinline__ void gload_lds16(const void* g, void* l) {
    __builtin_amdgcn_global_load_lds(
        (const __attribute__((address_space(1))) unsigned int*)g,
        (__attribute__((address_space(3))) unsigned int*)l, 16, 0, 0);
}

__device__ __forceinline__ unsigned pk_bf16(float a, float b) {
    unsigned lo = __bfloat16_as_ushort(__float2bfloat16(a));
    unsigned hi = __bfloat16_as_ushort(__float2bfloat16(b));
    return lo | (hi << 16);
}

// ---------------- weight transpose-convert: W[K][N] f32 -> Wt[N][K] bf16 ----
__global__ void wtrans_kernel(const float* __restrict__ W, bf16* __restrict__ Wt,
                              int K, int N) {
    __shared__ float tile[32][33];
    int n0 = blockIdx.x * 32, k0 = blockIdx.y * 32;
    int tx = threadIdx.x, ty = threadIdx.y;  // 32 x 8
#pragma unroll
    for (int i = 0; i < 32; i += 8)
        tile[ty + i][tx] = W[(size_t)(k0 + ty + i) * N + n0 + tx];
    __syncthreads();
#pragma unroll
    for (int i = 0; i < 32; i += 8)
        Wt[(size_t)(n0 + ty + i) * K + k0 + tx] = __float2bfloat16(tile[tx][ty + i]);
}

// ---------------- per-head V transpose: V[bh][t][64] -> Vt[bh][64][t] -------
__global__ void transpose_v_kernel(const bf16* __restrict__ V, bf16* __restrict__ Vt) {
    __shared__ bf16 tile[32][33];
    int bh = blockIdx.z;
    int t0 = blockIdx.x * 32;
    int d0 = blockIdx.y * 32;
    int tx = threadIdx.x, ty = threadIdx.y;  // 32 x 8
    const bf16* src = V + (size_t)bh * T_ * 64;
    bf16* dst = Vt + (size_t)bh * 64 * T_;
#pragma unroll
    for (int i = 0; i < 32; i += 8)
        tile[ty + i][tx] = src[(size_t)(t0 + ty + i) * 64 + d0 + tx];
    __syncthreads();
#pragma unroll
    for (int i = 0; i < 32; i += 8)
        dst[(size_t)(d0 + ty + i) * T_ + t0 + tx] = tile[tx][ty + i];
}

// ---------------- LayerNorm (row of 1024) f32 -> bf16 ----------------------
__global__ void ln_kernel(const float* __restrict__ x, const float* __restrict__ g,
                          const float* __restrict__ bta, bf16* __restrict__ out) {
    int row = blockIdx.x;
    int t = threadIdx.x;  // 256 threads * float4
    float4 v = ((const float4*)(x + (size_t)row * D_))[t];
    float s1 = v.x + v.y + v.z + v.w;
    float s2 = v.x * v.x + v.y * v.y + v.z * v.z + v.w * v.w;
#pragma unroll
    for (int m = 1; m < 64; m <<= 1) {
        s1 += __shfl_xor(s1, m);
        s2 += __shfl_xor(s2, m);
    }
    __shared__ float red[8];
    int wid = t >> 6, lane = t & 63;
    if (lane == 0) { red[wid] = s1; red[4 + wid] = s2; }
    __syncthreads();
    s1 = red[0] + red[1] + red[2] + red[3];
    s2 = red[4] + red[5] + red[6] + red[7];
    float mu = s1 * (1.0f / D_);
    float var = s2 * (1.0f / D_) - mu * mu;
    float rs = rsqrtf(var + 1e-5f);
    float4 gv = ((const float4*)g)[t];
    float4 bv = ((const float4*)bta)[t];
    bf16* o = out + (size_t)row * D_ + t * 4;
    o[0] = __float2bfloat16((v.x - mu) * rs * gv.x + bv.x);
    o[1] = __float2bfloat16((v.y - mu) * rs * gv.y + bv.y);
    o[2] = __float2bfloat16((v.z - mu) * rs * gv.z + bv.z);
    o[3] = __float2bfloat16((v.w - mu) * rs * gv.w + bv.w);
}

// ---------------- GEMM: C[M][N] = A[M][K](bf16) @ Bt[N][K](bf16)^T ----------
// min-2-phase: double-buffered LDS, prefetch tile s+1 (gload_lds) BEFORE
// computing tile s, ONE barrier per K-step (T3 minimum recipe). T2 XOR-swizzle
// kept (rule 21: linear dest, inverse-swizzled global source, same XOR on read).
// EPI 0: qkv head-scatter (bf16), Q pre-scaled by SCL.
// EPI 1: +bias +resid -> f32.  EPI 2: gelu(+bias) -> bf16.
template <int EPI, int BM>
__global__ __launch_bounds__(256) void gemm_bt(const bf16* __restrict__ A,
                                               const bf16* __restrict__ Bt,
                                               int N, int K,
                                               const float* __restrict__ bias,
                                               const float* __restrict__ resid,
                                               void* __restrict__ out) {
    constexpr int MF = BM / 32;                     // m-frags per wave
    __shared__ __align__(16) bf16 Asm[2][BM * 64];  // dbuf, swizzled content
    __shared__ __align__(16) bf16 Bsm[2][128 * 64];
    int tid = threadIdx.x;
    // XCD swizzle: contiguous chunks of the linear wg id per XCD (nwg % 8 == 0)
    int nwg = gridDim.x * gridDim.y;
    int wg = blockIdx.y * gridDim.x + blockIdx.x;
    int swz = (wg & 7) * (nwg >> 3) + (wg >> 3);
    int bm = (swz / gridDim.x) * BM;
    int bn = (swz % gridDim.x) * 128;
    int wid = tid >> 6, lane = tid & 63;
    int wr = wid >> 1, wc = wid & 1;
    f32x4 acc[MF][4];
#pragma unroll
    for (int m = 0; m < MF; m++)
#pragma unroll
        for (int n = 0; n < 4; n++) acc[m][n] = (f32x4){0.f, 0.f, 0.f, 0.f};

    auto stage = [&](int buf, int k0) {
#pragma unroll
        for (int i = 0; i < BM * 8 / 256; i++) {
            int c = tid + i * 256;
            int row = c >> 3;
            int sw = ((c & 7) ^ (row & 7)) * 8;   // inverse-swizzled source col
            gload_lds16(&A[(size_t)(bm + row) * K + k0 + sw], &Asm[buf][c * 8]);
        }
#pragma unroll
        for (int i = 0; i < 4; i++) {
            int c = tid + i * 256;
            int row = c >> 3;
            int sw = ((c & 7) ^ (row & 7)) * 8;
            gload_lds16(&Bt[(size_t)(bn + row) * K + k0 + sw], &Bsm[buf][c * 8]);
        }
    };

    stage(0, 0);
    __syncthreads();                                 // buf0 ready (vmcnt drain)
    int NS = K / 64;
    for (int s = 0; s < NS; s++) {
        int cur = s & 1;
        if (s + 1 < NS) stage(cur ^ 1, (s + 1) * 64);  // prefetch under compute
#pragma unroll
        for (int kk = 0; kk < 2; kk++) {
            int cc = kk * 4 + (lane >> 4);           // logical 16B-chunk index
            bf16x8 af[MF], bfr[4];
#pragma unroll
            for (int m = 0; m < MF; m++) {
                int ra = wr * (BM / 2) + m * 16 + (lane & 15);
                af[m] = *(const bf16x8*)&Asm[cur][ra * 64 + ((cc ^ (ra & 7)) * 8)];
            }
#pragma unroll
            for (int n = 0; n < 4; n++) {
                int rb = wc * 64 + n * 16 + (lane & 15);
                bfr[n] = *(const bf16x8*)&Bsm[cur][rb * 64 + ((cc ^ (rb & 7)) * 8)];
            }
#pragma unroll
            for (int m = 0; m < MF; m++)
#pragma unroll
                for (int n = 0; n < 4; n++)
                    acc[m][n] = __builtin_amdgcn_mfma_f32_16x16x32_bf16(af[m], bfr[n], acc[m][n], 0, 0, 0);
        }
        __syncthreads();   // prefetch landed + all waves done reading buf[cur]
    }
    int r0 = bm + wr * (BM / 2);
    int c0 = bn + wc * 64;
#pragma unroll
    for (int m = 0; m < MF; m++) {
#pragma unroll
        for (int n = 0; n < 4; n++) {
#pragma unroll
            for (int j = 0; j < 4; j++) {
                int r = r0 + m * 16 + (lane >> 4) * 4 + j;
                int c = c0 + n * 16 + (lane & 15);
                float v = acc[m][n][j];
                if constexpr (EPI == 0) {
                    int which = c >> 10, d = c & 1023;
                    int h = d >> 6, dh = d & 63;
                    int b = r >> 11, t = r & 2047;
                    if (which == 0) v *= SCL;   // pre-scale Q for exp2-domain attn
                    ((bf16*)out)[(((size_t)which * 32 + b * 16 + h) * 2048 + t) * 64 + dh] =
                        __float2bfloat16(v);
                } else if constexpr (EPI == 1) {
                    ((float*)out)[(size_t)r * N + c] = v + bias[c] + resid[(size_t)r * N + c];
                } else {
                    float u = v + bias[c];
                    float ge = 0.5f * u * (1.0f + erff(u * 0.70710678118f));
                    ((bf16*)out)[(size_t)r * N + c] = __float2bfloat16(ge);
                }
            }
        }
    }
}

// ---------------- flash attention: 8 waves, 128 q-rows/block, KVBLK=64 ------
// Swapped QK^T (lane-local softmax) + T14 async-stage: prefetch K/V tile t+1
// into regs right after the LDS write of tile t; vmcnt wait lands at next
// iteration's ds_write, fully overlapped with compute.
__global__ __launch_bounds__(512) void attn_kernel(const bf16* __restrict__ Q,
                                                   const bf16* __restrict__ Kt,
                                                   const bf16* __restrict__ Vt,
                                                   bf16* __restrict__ Y) {
    __shared__ __align__(16) bf16 Ksm[64][72];
    __shared__ __align__(16) bf16 Vsm[64][72];       // Vsm[dh][key]
    __shared__ __align__(16) bf16 Psm[8][16][72];    // per-wave P[q][key]
    int tid = threadIdx.x;
    int wid = tid >> 6, lane = tid & 63;
    int bh = blockIdx.y;
    int q0 = blockIdx.x * 128 + wid * 16;
    const bf16* Qb = Q + (size_t)bh * T_ * 64;
    const bf16* Kb = Kt + (size_t)bh * T_ * 64;
    const bf16* Vb = Vt + (size_t)bh * 64 * T_;

    bf16x8 aq[2];   // used as B operand (cols = q)
#pragma unroll
    for (int kk = 0; kk < 2; kk++)
        aq[kk] = *(const bf16x8*)&Qb[(size_t)(q0 + (lane & 15)) * 64 + kk * 32 + (lane >> 4) * 8];

    float mrow = -1e30f, lrow = 0.f;
    f32x4 o[4];
#pragma unroll
    for (int n = 0; n < 4; n++) o[n] = (f32x4){0.f, 0.f, 0.f, 0.f};

    int srow = tid >> 3, scol8 = (tid & 7) * 8;
    uint4 kreg = *(const uint4*)&Kb[(size_t)srow * 64 + scol8];
    uint4 vreg = *(const uint4*)&Vb[(size_t)srow * T_ + scol8];

    for (int kt = 0; kt < T_ / 64; kt++) {
        __syncthreads();          // all reads of LDS from prev iter done
        *(uint4*)&Ksm[srow][scol8] = kreg;
        *(uint4*)&Vsm[srow][scol8] = vreg;
        if (kt + 1 < T_ / 64) {   // T14: issue next-tile loads under compute
            kreg = *(const uint4*)&Kb[(size_t)((kt + 1) * 64 + srow) * 64 + scol8];
            vreg = *(const uint4*)&Vb[(size_t)srow * T_ + (kt + 1) * 64 + scol8];
        }
        __syncthreads();          // LDS writes visible

        f32x4 s[4];
        __builtin_amdgcn_s_setprio(1);
#pragma unroll
        for (int n = 0; n < 4; n++) {
            bf16x8 k0f = *(const bf16x8*)&Ksm[n * 16 + (lane & 15)][(lane >> 4) * 8];
            bf16x8 k1f = *(const bf16x8*)&Ksm[n * 16 + (lane & 15)][32 + (lane >> 4) * 8];
            s[n] = __builtin_amdgcn_mfma_f32_16x16x32_bf16(k0f, aq[0], (f32x4){0.f, 0.f, 0.f, 0.f}, 0, 0, 0);
            s[n] = __builtin_amdgcn_mfma_f32_16x16x32_bf16(k1f, aq[1], s[n], 0, 0, 0);
        }
        __builtin_amdgcn_s_setprio(0);

        // in-lane max over 16 keys, then combine the 4 lane-groups
        float my = fmaxf(fmaxf(fmaxf(s[0][0], s[0][1]), fmaxf(s[0][2], s[0][3])),
                         fmaxf(fmaxf(s[1][0], s[1][1]), fmaxf(s[1][2], s[1][3])));
        float my2 = fmaxf(fmaxf(fmaxf(s[2][0], s[2][1]), fmaxf(s[2][2], s[2][3])),
                          fmaxf(fmaxf(s[3][0], s[3][1]), fmaxf(s[3][2], s[3][3])));
        my = fmaxf(my, my2);
        my = fmaxf(my, __shfl_xor(my, 16));
        my = fmaxf(my, __shfl_xor(my, 32));

        // T13 defer-max: rescale only when the running max grew by > 8 (log2)
        if (__any(my - mrow > 8.0f)) {
            float mn = fmaxf(mrow, my);
            float sc = exp2f(mrow - mn);
            mrow = mn;
            lrow *= sc;
#pragma unroll
            for (int j = 0; j < 4; j++) {
                float scj = __shfl(sc, (lane >> 4) * 4 + j);
#pragma unroll
                for (int n = 0; n < 4; n++) o[n][j] *= scj;
            }
        }

        float psum = 0.f;
#pragma unroll
        for (int n = 0; n < 4; n++)
#pragma unroll
            for (int j = 0; j < 4; j++) {
                float pv = exp2f(s[n][j] - mrow);
                s[n][j] = pv;
                psum += pv;
            }
        psum += __shfl_xor(psum, 16);
        psum += __shfl_xor(psum, 32);
        lrow += psum;

        // P -> LDS: one b64 per n (4 consecutive keys packed as bf16)
#pragma unroll
        for (int n = 0; n < 4; n++) {
            uint2 w;
            w.x = pk_bf16(s[n][0], s[n][1]);
            w.y = pk_bf16(s[n][2], s[n][3]);
            *(uint2*)&Psm[wid][lane & 15][n * 16 + (lane >> 4) * 4] = w;
        }

        bf16x8 pa[2];
#pragma unroll
        for (int kk = 0; kk < 2; kk++)
            pa[kk] = *(const bf16x8*)&Psm[wid][lane & 15][kk * 32 + (lane >> 4) * 8];

        __builtin_amdgcn_s_setprio(1);
#pragma unroll
        for (int n = 0; n < 4; n++) {
            bf16x8 v0 = *(const bf16x8*)&Vsm[n * 16 + (lane & 15)][(lane >> 4) * 8];
            bf16x8 v1 = *(const bf16x8*)&Vsm[n * 16 + (lane & 15)][32 + (lane >> 4) * 8];
            o[n] = __builtin_amdgcn_mfma_f32_16x16x32_bf16(pa[0], v0, o[n], 0, 0, 0);
            o[n] = __builtin_amdgcn_mfma_f32_16x16x32_bf16(pa[1], v1, o[n], 0, 0, 0);
        }
        __builtin_amdgcn_s_setprio(0);
    }

    int b = bh >> 4, h = bh & 15;
#pragma unroll
    for (int j = 0; j < 4; j++) {
        float lj = __shfl(lrow, (lane >> 4) * 4 + j);
        float inv = 1.0f / lj;
        int t = q0 + (lane >> 4) * 4 + j;
#pragma unroll
        for (int n = 0; n < 4; n++) {
            int c = h * 64 + n * 16 + (lane & 15);
            Y[((size_t)b * T_ + t) * D_ + c] = __float2bfloat16(o[n][j] * inv);
        }
    }
}

// ---------------------------------------------------------------------------
extern "C" void kernel_launch(void* const* d_in, const int* in_sizes, int n_in,
                              void* d_out, int out_size, void* d_ws, size_t ws_size,
                              hipStream_t stream) {
    const float* inputs = (const float*)d_in[0];
    // d_in[1] cond, d_in[2] attention_mask: unused by reference path
    const float* ln1_g = (const float*)d_in[3];
    const float* ln1_b = (const float*)d_in[4];
    const float* ln2_g = (const float*)d_in[5];
    const float* ln2_b = (const float*)d_in[6];
    const float* w_qkv = (const float*)d_in[7];
    const float* w_out = (const float*)d_in[8];
    const float* b_out = (const float*)d_in[9];
    const float* w1    = (const float*)d_in[10];
    const float* b1    = (const float*)d_in[11];
    const float* w2    = (const float*)d_in[12];
    const float* b2    = (const float*)d_in[13];

    char* p = (char*)d_ws;
    auto alloc = [&](size_t bytes) {
        void* r = (void*)p;
        p += (bytes + 255) & ~(size_t)255;
        return r;
    };
    bf16* x1     = (bf16*)alloc((size_t)ROWS * D_ * 2);
    bf16* wqkv_t = (bf16*)alloc((size_t)3 * D_ * D_ * 2);
    bf16* wout_t = (bf16*)alloc((size_t)D_ * D_ * 2);
    bf16* w1_t   = (bf16*)alloc((size_t)MLP_ * D_ * 2);
    bf16* w2_t   = (bf16*)alloc((size_t)D_ * MLP_ * 2);
    bf16* qkv    = (bf16*)alloc((size_t)3 * BHTD * 2);
    bf16* vt     = (bf16*)alloc((size_t)BHTD * 2);
    bf16* y      = (bf16*)alloc((size_t)ROWS * D_ * 2);
    float* x2    = (float*)alloc((size_t)ROWS * D_ * 4);
    bf16* h2     = (bf16*)alloc((size_t)ROWS * D_ * 2);
    bf16* act    = (bf16*)alloc((size_t)ROWS * MLP_ * 2);

    dim3 tb(32, 8);
    wtrans_kernel<<<dim3(3 * D_ / 32, D_ / 32), tb, 0, stream>>>(w_qkv, wqkv_t, D_, 3 * D_);
    wtrans_kernel<<<dim3(D_ / 32, D_ / 32), tb, 0, stream>>>(w_out, wout_t, D_, D_);
    wtrans_kernel<<<dim3(MLP_ / 32, D_ / 32), tb, 0, stream>>>(w1, w1_t, D_, MLP_);
    wtrans_kernel<<<dim3(D_ / 32, MLP_ / 32), tb, 0, stream>>>(w2, w2_t, MLP_, D_);

    ln_kernel<<<ROWS, 256, 0, stream>>>(inputs, ln1_g, ln1_b, x1);

    gemm_bt<0, 128><<<dim3(3 * D_ / 128, ROWS / 128), 256, 0, stream>>>(
        x1, wqkv_t, 3 * D_, D_, nullptr, nullptr, (void*)qkv);

    transpose_v_kernel<<<dim3(T_ / 32, 2, 32), tb, 0, stream>>>(qkv + 2 * BHTD, vt);

    attn_kernel<<<dim3(T_ / 128, 32), 512, 0, stream>>>(qkv, qkv + BHTD, vt, y);

    gemm_bt<1, 64><<<dim3(D_ / 128, ROWS / 64), 256, 0, stream>>>(
        y, wout_t, D_, D_, b_out, inputs, (void*)x2);

    ln_kernel<<<ROWS, 256, 0, stream>>>(x2, ln2_g, ln2_b, h2);

    gemm_bt<2, 128><<<dim3(MLP_ / 128, ROWS / 128), 256, 0, stream>>>(
        h2, w1_t, MLP_, D_, b1, nullptr, (void*)act);

    gemm_bt<1, 64><<<dim3(D_ / 128, ROWS / 64), 256, 0, stream>>>(
        act, w2_t, D_, MLP_, b2, x2, d_out);
}